// Round 10
// baseline (442.078 us; speedup 1.0000x reference)
//
#include <hip/hip_runtime.h>
#include <stdint.h>

#define N_NODES 50000
#define N_EDGES 400000
#define NBLK_SC 196        // ceil(50000/256)
#define MT128   391        // ceil(50000/128) m-tiles
// prep blocks: 25000 cvt | 64 cewWt | 128 W1t | 128 W2t | 448 Wcat | 8 Wft | 1563 count
#define NPREP   27339

typedef unsigned short u16;
typedef __attribute__((ext_vector_type(8))) short short8;
typedef __attribute__((ext_vector_type(4))) float f32x4;

__device__ __forceinline__ float b2f(u16 u){ unsigned int x=((unsigned int)u)<<16; float f; __builtin_memcpy(&f,&x,4); return f; }
__device__ __forceinline__ u16 f2b(float f){ unsigned int x; __builtin_memcpy(&x,&f,4); x += 0x7fffu + ((x>>16)&1u); return (u16)(x>>16); }
// unpack 2 bf16 from one dword: lo = bits[15:0], hi = bits[31:16]
__device__ __forceinline__ float blo(unsigned int x){ unsigned int y = x<<16; float f; __builtin_memcpy(&f,&y,4); return f; }
__device__ __forceinline__ float bhi(unsigned int x){ unsigned int y = x & 0xffff0000u; float f; __builtin_memcpy(&f,&y,4); return f; }

// ---------------- utility ----------------
__global__ void k_zeroi(int* __restrict__ p, int n){
  int i = blockIdx.x*256+threadIdx.x;
  if (i < n) p[i] = 0;
}
__global__ void k_fillf(float* __restrict__ p, int n, float v){
  int i = blockIdx.x*256+threadIdx.x;
  if (i < n) p[i] = v;
}

// ---------------- fused prep: cvt_x | weight transposes | Wf transpose | edge count ----------
__global__ __launch_bounds__(256)
void k_prep(const float* __restrict__ x, u16* __restrict__ xb,
            const float* __restrict__ cewW, u16* __restrict__ cewWt,
            const float* __restrict__ W1, u16* __restrict__ W1t,
            const float* __restrict__ W2, u16* __restrict__ W2t,
            const float* __restrict__ Wq, const float* __restrict__ Wk,
            const float* __restrict__ Wv, const float* __restrict__ Wsk,
            u16* __restrict__ Wcat,
            const float* __restrict__ Wf, float* __restrict__ Wft,
            const int* __restrict__ dst, int* __restrict__ cnt)
{
  int b = blockIdx.x, t = threadIdx.x;
  if (b < 25000){                       // cvt_x: 50000*128 = 6,400,000 = 25000*256 exact
    int i = b*256+t;
    xb[i] = f2b(x[i]);
    return;
  }
  b -= 25000;
  if (b < 64){                          // cewWt[n*128+k] = cewW[k*128+n]
    int i = b*256+t;
    int n = i >> 7, k = i & 127;
    cewWt[i] = f2b(cewW[k*128 + n]);
    return;
  }
  b -= 64;
  if (b < 128){                         // W1t[n*128+k] = W1[k*256+n]
    int i = b*256+t;
    int n = i >> 7, k = i & 127;
    W1t[i] = f2b(W1[k*256 + n]);
    return;
  }
  b -= 128;
  if (b < 128){                         // W2t[n*256+k] = W2[k*128+n]
    int i = b*256+t;
    int n = i >> 8, k = i & 255;
    W2t[i] = f2b(W2[k*128 + n]);
    return;
  }
  b -= 128;
  if (b < 448){                         // Wcat[896*128]
    int i = b*256+t;
    int n = i >> 7, k = i & 127;
    float v = 0.f;
    if      (n < 256) v = Wq[k*256 + n];
    else if (n < 512) v = Wk[k*256 + (n-256)];
    else if (n < 768) v = Wv[k*256 + (n-512)];
    else if (n < 832) v = Wsk[k*64 + (n-768)];
    Wcat[i] = f2b(v);
    return;
  }
  b -= 448;
  if (b < 8){                           // Wft[c*64+k] = Wf[k*32+c], 2048 fp32
    int i = b*256+t;
    int c = i >> 6, k = i & 63;
    Wft[i] = Wf[k*32 + c];
    return;
  }
  b -= 8;
  {                                     // count: 1563 blocks
    int e = b*256+t;
    if (e < N_EDGES) atomicAdd(&cnt[dst[e]], 1);
  }
}

// ---------------- CSR build ----------------
__global__ void k_scan1(const int* __restrict__ cnt, int* __restrict__ ro, int* __restrict__ bsums){
  __shared__ int sm[256];
  int b = blockIdx.x, t = threadIdx.x, i = b*256+t;
  int v = (i < N_NODES) ? cnt[i] : 0;
  sm[t] = v; __syncthreads();
  for (int off=1; off<256; off<<=1){
    int x = 0; if (t>=off) x = sm[t-off];
    __syncthreads();
    if (t>=off) sm[t] += x;
    __syncthreads();
  }
  if (i < N_NODES) ro[i] = sm[t]-v;
  if (t==255) bsums[b] = sm[255];
}
// scan2+scan3 merged: each block redundantly prefix-scans the 196 block sums in LDS.
__global__ void k_scan23(int* __restrict__ ro, const int* __restrict__ bsums, int nb){
  __shared__ int sm[256];
  int b = blockIdx.x, t = threadIdx.x, i = b*256+t;
  int v = (t<nb) ? bsums[t] : 0;
  sm[t]=v; __syncthreads();
  for (int off=1; off<256; off<<=1){
    int x = 0; if (t>=off) x = sm[t-off];
    __syncthreads();
    if (t>=off) sm[t] += x;
    __syncthreads();
  }
  int offset = (b==0) ? 0 : sm[b-1];
  if (i < N_NODES) ro[i] += offset;
  if (i == 0) ro[N_NODES] = N_EDGES;
}
__global__ void k_scatter(const int* __restrict__ src, const int* __restrict__ dst,
                          const int* __restrict__ ro, int* __restrict__ cursor,
                          int* __restrict__ perm){
  int e = blockIdx.x*256+threadIdx.x;
  if (e >= N_EDGES) return;
  int d = dst[e];
  int pos = ro[d] + atomicAdd(&cursor[d], 1);
  perm[pos] = src[e];
}

// ---------------- MFMA GEMM with fused row-dot epilogue ----------------
// Swapped-operand MFMA: lane owns 1 row x 4 consecutive cols; ushort4 stores.
// MODE 1 (cew):  s[mm] += dot(h_row, attS[128]) via atomicAdd (dS pre-zeroed)
// MODE 2 (gat1): head=nTile*2+wc (4x64); plain stores dS/dD[mm*4+head]
// MODE 3 (gat2): heads 2wc,2wc+1 (4x32); plain stores
// Lanes {l,l+16,l+32,l+48} jointly cover a head's cols -> shfl_xor(16/32) completes the dot.
template<int MODE>
__global__ __launch_bounds__(256)
void k_gemm_rd(const u16* __restrict__ A, const u16* __restrict__ Bt,
               const float* __restrict__ bias, u16* __restrict__ C,
               int K, int Nst, int nTiles,
               const float* __restrict__ attS, const float* __restrict__ attD,
               float* __restrict__ dS, float* __restrict__ dD)
{
  __shared__ u16 sA[128][40];
  __shared__ u16 sB[128][40];
  int t = threadIdx.x, lane = t & 63, wave = t >> 6;
  int wr = wave >> 1, wc = wave & 1;
  int mTile = blockIdx.x / nTiles, nTile = blockIdx.x - mTile*nTiles;
  int mBase = mTile*128, nBase = nTile*128;
  f32x4 acc[4][4] = {};
  const int row = lane & 15, kq = (lane >> 4) * 8;
  for (int k0 = 0; k0 < K; k0 += 32){
    #pragma unroll
    for (int it = 0; it < 2; ++it){
      int c = it*256 + t;
      int m = c >> 2, ko = (c & 3) * 8;
      int ra = mBase + m;
      uint4 va = {0u,0u,0u,0u};
      if (ra < N_NODES) va = *(const uint4*)(A + (size_t)ra*K + k0 + ko);
      *(uint4*)&sA[m][ko] = va;
      *(uint4*)&sB[m][ko] = *(const uint4*)(Bt + (size_t)(nBase+m)*K + k0 + ko);
    }
    __syncthreads();
    short8 af[4], bfr[4];
    #pragma unroll
    for (int i=0;i<4;i++) af[i]  = *(const short8*)&sA[wr*64 + i*16 + row][kq];
    #pragma unroll
    for (int i=0;i<4;i++) bfr[i] = *(const short8*)&sB[wc*64 + i*16 + row][kq];
    #pragma unroll
    for (int i=0;i<4;i++)
      #pragma unroll
      for (int j=0;j<4;j++)
        acc[i][j] = __builtin_amdgcn_mfma_f32_16x16x32_bf16(bfr[j], af[i], acc[i][j], 0,0,0);
    __syncthreads();
  }
  const int mcol = lane & 15, ngrp = (lane >> 4) * 4;
  float4 bv4[4];
  #pragma unroll
  for (int j=0;j<4;j++){
    if (bias) bv4[j] = *(const float4*)(bias + nBase + wc*64 + j*16 + ngrp);
    else { bv4[j].x=0.f; bv4[j].y=0.f; bv4[j].z=0.f; bv4[j].w=0.f; }
  }
  // C store
  #pragma unroll
  for (int j=0;j<4;j++){
    int nn = nBase + wc*64 + j*16 + ngrp;
    #pragma unroll
    for (int i=0;i<4;i++){
      int mm = mBase + wr*64 + i*16 + mcol;
      if (mm >= N_NODES) continue;
      f32x4 a = acc[i][j];
      ushort4 ov = { f2b(a[0]+bv4[j].x), f2b(a[1]+bv4[j].y), f2b(a[2]+bv4[j].z), f2b(a[3]+bv4[j].w) };
      *(ushort4*)(C + (size_t)mm*Nst + nn) = ov;
    }
  }
  // fused row-dot epilogue
  if constexpr (MODE == 1){
    float avS[16];
    #pragma unroll
    for (int j=0;j<4;j++)
      #pragma unroll
      for (int r=0;r<4;r++)
        avS[j*4+r] = attS[wc*64 + j*16 + ngrp + r];
    #pragma unroll
    for (int i=0;i<4;i++){
      float p = 0.f;
      #pragma unroll
      for (int j=0;j<4;j++){
        f32x4 a = acc[i][j];
        p += (a[0]+bv4[j].x)*avS[j*4+0] + (a[1]+bv4[j].y)*avS[j*4+1]
           + (a[2]+bv4[j].z)*avS[j*4+2] + (a[3]+bv4[j].w)*avS[j*4+3];
      }
      p += __shfl_xor(p,16); p += __shfl_xor(p,32);
      int mm = mBase + wr*64 + i*16 + mcol;
      if (lane < 16 && mm < N_NODES) atomicAdd(&dS[mm], p);
    }
  }
  if constexpr (MODE == 2){
    int head = nTile*2 + wc;
    float avS[16], avD[16];
    #pragma unroll
    for (int j=0;j<4;j++)
      #pragma unroll
      for (int r=0;r<4;r++){
        int c = j*16 + ngrp + r;
        avS[j*4+r] = attS[head*64 + c];
        avD[j*4+r] = attD[head*64 + c];
      }
    #pragma unroll
    for (int i=0;i<4;i++){
      float ps = 0.f, pd = 0.f;
      #pragma unroll
      for (int j=0;j<4;j++){
        f32x4 a = acc[i][j];
        ps += a[0]*avS[j*4+0] + a[1]*avS[j*4+1] + a[2]*avS[j*4+2] + a[3]*avS[j*4+3];
        pd += a[0]*avD[j*4+0] + a[1]*avD[j*4+1] + a[2]*avD[j*4+2] + a[3]*avD[j*4+3];
      }
      ps += __shfl_xor(ps,16); ps += __shfl_xor(ps,32);
      pd += __shfl_xor(pd,16); pd += __shfl_xor(pd,32);
      int mm = mBase + wr*64 + i*16 + mcol;
      if (lane < 16 && mm < N_NODES){
        dS[mm*4 + head] = ps;
        dD[mm*4 + head] = pd;
      }
    }
  }
  if constexpr (MODE == 3){
    float avS[16], avD[16];
    #pragma unroll
    for (int j=0;j<4;j++)
      #pragma unroll
      for (int r=0;r<4;r++){
        int head = 2*wc + (j>>1);
        int c = (j&1)*16 + ngrp + r;
        avS[j*4+r] = attS[head*32 + c];
        avD[j*4+r] = attD[head*32 + c];
      }
    #pragma unroll
    for (int i=0;i<4;i++){
      float ps0=0.f, ps1=0.f, pd0=0.f, pd1=0.f;
      #pragma unroll
      for (int j=0;j<2;j++){
        f32x4 a = acc[i][j];
        ps0 += a[0]*avS[j*4+0] + a[1]*avS[j*4+1] + a[2]*avS[j*4+2] + a[3]*avS[j*4+3];
        pd0 += a[0]*avD[j*4+0] + a[1]*avD[j*4+1] + a[2]*avD[j*4+2] + a[3]*avD[j*4+3];
      }
      #pragma unroll
      for (int j=2;j<4;j++){
        f32x4 a = acc[i][j];
        ps1 += a[0]*avS[j*4+0] + a[1]*avS[j*4+1] + a[2]*avS[j*4+2] + a[3]*avS[j*4+3];
        pd1 += a[0]*avD[j*4+0] + a[1]*avD[j*4+1] + a[2]*avD[j*4+2] + a[3]*avD[j*4+3];
      }
      ps0 += __shfl_xor(ps0,16); ps0 += __shfl_xor(ps0,32);
      ps1 += __shfl_xor(ps1,16); ps1 += __shfl_xor(ps1,32);
      pd0 += __shfl_xor(pd0,16); pd0 += __shfl_xor(pd0,32);
      pd1 += __shfl_xor(pd1,16); pd1 += __shfl_xor(pd1,32);
      int mm = mBase + wr*64 + i*16 + mcol;
      if (lane < 16 && mm < N_NODES){
        dS[mm*4 + 2*wc    ] = ps0;
        dS[mm*4 + 2*wc + 1] = ps1;
        dD[mm*4 + 2*wc    ] = pd0;
        dD[mm*4 + 2*wc + 1] = pd1;
      }
    }
  }
}

// fused q|k|v|skip GEMM: K=128, 896 output cols routed to 3 buffers.
// kvb row = [k 0..255 | v 256..511] (contiguous regions -> block-dense writes).
__global__ __launch_bounds__(256)
void k_gemm_qkvs(const u16* __restrict__ A, const u16* __restrict__ Bt,
                 const float* __restrict__ bq, const float* __restrict__ bk,
                 const float* __restrict__ bv,
                 u16* __restrict__ qb, u16* __restrict__ kvb,
                 u16* __restrict__ skipb)
{
  __shared__ u16 sA[128][40];
  __shared__ u16 sB[128][40];
  int t = threadIdx.x, lane = t & 63, wave = t >> 6;
  int wr = wave >> 1, wc = wave & 1;
  int mTile = blockIdx.x / 7, nTile = blockIdx.x - mTile*7;
  int mBase = mTile*128, nBase = nTile*128;
  f32x4 acc[4][4] = {};
  const int row = lane & 15, kq = (lane >> 4) * 8;
  const int K = 128;
  for (int k0 = 0; k0 < K; k0 += 32){
    #pragma unroll
    for (int it = 0; it < 2; ++it){
      int c = it*256 + t;
      int m = c >> 2, ko = (c & 3) * 8;
      int ra = mBase + m;
      uint4 va = {0u,0u,0u,0u};
      if (ra < N_NODES) va = *(const uint4*)(A + (size_t)ra*K + k0 + ko);
      *(uint4*)&sA[m][ko] = va;
      *(uint4*)&sB[m][ko] = *(const uint4*)(Bt + (size_t)(nBase+m)*K + k0 + ko);
    }
    __syncthreads();
    short8 af[4], bfr[4];
    #pragma unroll
    for (int i=0;i<4;i++) af[i]  = *(const short8*)&sA[wr*64 + i*16 + row][kq];
    #pragma unroll
    for (int i=0;i<4;i++) bfr[i] = *(const short8*)&sB[wc*64 + i*16 + row][kq];
    #pragma unroll
    for (int i=0;i<4;i++)
      #pragma unroll
      for (int j=0;j<4;j++)
        acc[i][j] = __builtin_amdgcn_mfma_f32_16x16x32_bf16(bfr[j], af[i], acc[i][j], 0,0,0);
    __syncthreads();
  }
  const int mcol = lane & 15, ngrp = (lane >> 4) * 4;
  #pragma unroll
  for (int j=0;j<4;j++){
    int nn = nBase + wc*64 + j*16 + ngrp;
    u16* dst; int stride, col; float4 bb = {0.f,0.f,0.f,0.f};
    if      (nn < 256){ dst=qb;    stride=256; col=nn;     bb = *(const float4*)(bq + col); }
    else if (nn < 512){ dst=kvb;   stride=512; col=nn-256; bb = *(const float4*)(bk + (nn-256)); }
    else if (nn < 768){ dst=kvb;   stride=512; col=nn-256; bb = *(const float4*)(bv + (nn-512)); }
    else if (nn < 832){ dst=skipb; stride=64;  col=nn-768; }
    else continue;
    #pragma unroll
    for (int i=0;i<4;i++){
      int mm = mBase + wr*64 + i*16 + mcol;
      if (mm >= N_NODES) continue;
      f32x4 a = acc[i][j];
      ushort4 ov = { f2b(a[0]+bb.x), f2b(a[1]+bb.y), f2b(a[2]+bb.z), f2b(a[3]+bb.w) };
      *(ushort4*)(dst + (size_t)mm*stride + col) = ov;
    }
  }
}

// ---------------- layer-0 aggregation: no-max softmax, 8-edge batched ----------------
__global__ __launch_bounds__(256)
void k_agg_cew(const u16* __restrict__ h0, const float* __restrict__ s, const float* __restrict__ cewf,
               const int* __restrict__ ro, const int* __restrict__ perm, u16* __restrict__ x1)
{
  int wave = threadIdx.x>>6, lane = threadIdx.x&63;
  int node = blockIdx.x*4 + wave;
  if (node >= N_NODES) return;
  float sd = s[node], cd = cewf[node];
  int beg = ro[node], end = ro[node+1];
  int f = 2*lane;
  float d = 0.f, a0 = 0.f, a1 = 0.f;
  for (int cbeg = beg; cbeg < end; cbeg += 64){
    int j = cbeg + lane;
    float wl = 0.f; int u = 0;
    if (j < end){
      u = perm[j];
      float a = s[u] + sd; a = a>=0.f ? a : 0.01f*a;
      wl = __expf(a * (cewf[u] + cd));
    }
    int cnt = end - cbeg; if (cnt > 64) cnt = 64;
    for (int e=0; e<cnt; e+=8){
      float ww[8]; int uu[8];
      #pragma unroll
      for (int q=0;q<8;q++){ ww[q]=__shfl(wl,e+q); uu[q]=__shfl(u,e+q); }
      unsigned int tv[8];
      #pragma unroll
      for (int q=0;q<8;q++) tv[q] = *(const unsigned int*)(h0 + (size_t)uu[q]*128 + f);
      #pragma unroll
      for (int q=0;q<8;q++){
        d  += ww[q];
        a0 += ww[q]*b2f((u16)(tv[q]&0xffffu));
        a1 += ww[q]*b2f((u16)(tv[q]>>16));
      }
    }
  }
  float inv = 1.f/(d + 1e-16f);
  float o0 = a0*inv; o0 = o0>0.f?o0:0.f;
  float o1 = a1*inv; o1 = o1>0.f?o1:0.f;
  *(unsigned int*)(x1 + (size_t)node*128 + f) = (unsigned int)f2b(o0) | ((unsigned int)f2b(o1)<<16);
}

// ---------------- GAT aggregation, head-parallel, no-max softmax, 8-edge batched ----------------
__global__ __launch_bounds__(256)
void k_agg_gat1(const u16* __restrict__ hb, const float* __restrict__ aS, const float* __restrict__ aD,
                const float* __restrict__ bias, const int* __restrict__ ro, const int* __restrict__ perm,
                u16* __restrict__ out)
{
  int wave = threadIdx.x>>6, lane = threadIdx.x&63;
  int node = blockIdx.x*4 + wave;
  if (node >= N_NODES) return;
  int h = lane >> 4, l = lane & 15, grp = h << 4;
  auto lk = [](float x){ return x>=0.f ? x : 0.2f*x; };
  float ad = aD[node*4+h];
  float sw = __expf(lk(aS[node*4+h] + ad));   // self-loop weight
  int beg = ro[node], end = ro[node+1];
  int fo = h*64 + l*4;
  float d = sw;
  float c0,c1,c2,c3;
  { ushort4 pv = *(const ushort4*)(hb + (size_t)node*256 + fo);
    c0=sw*b2f(pv.x); c1=sw*b2f(pv.y); c2=sw*b2f(pv.z); c3=sw*b2f(pv.w); }
  for (int cbeg = beg; cbeg < end; cbeg += 16){
    int j = cbeg + l;
    float wl = 0.f; int u = 0;
    if (j < end){ u = perm[j]; wl = __expf(lk(aS[u*4+h] + ad)); }
    int cnt = end - cbeg; if (cnt > 16) cnt = 16;
    for (int e=0; e<cnt; e+=8){
      float ww[8]; int uu[8];
      #pragma unroll
      for (int q=0;q<8;q++){ ww[q]=__shfl(wl,grp+e+q); uu[q]=__shfl(u,grp+e+q); }
      ushort4 tv[8];
      #pragma unroll
      for (int q=0;q<8;q++) tv[q] = *(const ushort4*)(hb + (size_t)uu[q]*256 + fo);
      #pragma unroll
      for (int q=0;q<8;q++){
        d  += ww[q];
        c0 += ww[q]*b2f(tv[q].x);
        c1 += ww[q]*b2f(tv[q].y);
        c2 += ww[q]*b2f(tv[q].z);
        c3 += ww[q]*b2f(tv[q].w);
      }
    }
  }
  float inv = 1.f/(d + 1e-16f);
  float o0 = c0*inv + bias[fo+0]; o0 = o0>0.f?o0:0.f;
  float o1 = c1*inv + bias[fo+1]; o1 = o1>0.f?o1:0.f;
  float o2 = c2*inv + bias[fo+2]; o2 = o2>0.f?o2:0.f;
  float o3 = c3*inv + bias[fo+3]; o3 = o3>0.f?o3:0.f;
  ushort4 ov = { f2b(o0), f2b(o1), f2b(o2), f2b(o3) };
  *(ushort4*)(out + (size_t)node*256 + fo) = ov;
}

__global__ __launch_bounds__(256)
void k_agg_gat2(const u16* __restrict__ hb, const float* __restrict__ aS, const float* __restrict__ aD,
                const float* __restrict__ bias, const int* __restrict__ ro, const int* __restrict__ perm,
                u16* __restrict__ out)
{
  int wave = threadIdx.x>>6, lane = threadIdx.x&63;
  int node = blockIdx.x*4 + wave;
  if (node >= N_NODES) return;
  int h = lane >> 4, l = lane & 15, grp = h << 4;
  auto lk = [](float x){ return x>=0.f ? x : 0.2f*x; };
  float ad = aD[node*4+h];
  float sw = __expf(lk(aS[node*4+h] + ad));
  int beg = ro[node], end = ro[node+1];
  int fo = h*32 + l*2;
  float d = sw;
  float c0,c1;
  { unsigned int pv = *(const unsigned int*)(hb + (size_t)node*128 + fo);
    c0 = sw*b2f((u16)(pv & 0xffffu)); c1 = sw*b2f((u16)(pv >> 16)); }
  for (int cbeg = beg; cbeg < end; cbeg += 16){
    int j = cbeg + l;
    float wl = 0.f; int u = 0;
    if (j < end){ u = perm[j]; wl = __expf(lk(aS[u*4+h] + ad)); }
    int cnt = end - cbeg; if (cnt > 16) cnt = 16;
    for (int e=0; e<cnt; e+=8){
      float ww[8]; int uu[8];
      #pragma unroll
      for (int q=0;q<8;q++){ ww[q]=__shfl(wl,grp+e+q); uu[q]=__shfl(u,grp+e+q); }
      unsigned int tv[8];
      #pragma unroll
      for (int q=0;q<8;q++) tv[q] = *(const unsigned int*)(hb + (size_t)uu[q]*128 + fo);
      #pragma unroll
      for (int q=0;q<8;q++){
        d  += ww[q];
        c0 += ww[q]*b2f((u16)(tv[q]&0xffffu));
        c1 += ww[q]*b2f((u16)(tv[q]>>16));
      }
    }
  }
  float inv = 1.f/(d + 1e-16f);
  float o0 = c0*inv + bias[fo+0]; o0 = o0>0.f?o0:0.f;
  float o1 = c1*inv + bias[fo+1]; o1 = o1>0.f?o1:0.f;
  *(unsigned int*)(out + (size_t)node*128 + fo) = (unsigned int)f2b(o0) | ((unsigned int)f2b(o1)<<16);
}

// ---------------- transformer conv + fused final linear (64->32, fp32 out) ----------------
// 4-edge batch, K/V contiguous regions. Final linear via LDS stage:
// quad-0 lanes write the 64-float row (one f32x4 each) to LDS; every lane reads its
// k-half back as 8x ds_read_b128 (broadcast addrs, conflict-free) and multiplies with
// pre-transposed Wft[c*64+k] (float4 loads, L1-hot). Replaces R9's 32 ds_bpermute +
// 32 scalar Wf loads. Same-wave producer/consumer -> no barrier needed.
__global__ __launch_bounds__(256)
void k_tr(const u16* __restrict__ qb, const u16* __restrict__ kvb,
          const u16* __restrict__ skipb, const float* __restrict__ bsk,
          const int* __restrict__ ro, const int* __restrict__ perm,
          const float* __restrict__ Wft, const float* __restrict__ bf,
          float* __restrict__ out)
{
  __shared__ float smx[4][64];
  int wave = threadIdx.x>>6, lane = threadIdx.x&63;
  int node = blockIdx.x*4 + wave;
  if (node >= N_NODES) return;
  int h = lane >> 4, l = lane & 15;
  int fo = h*64 + l*4;
  ushort4 qv = *(const ushort4*)(qb + (size_t)node*256 + fo);
  float q0=b2f(qv.x), q1=b2f(qv.y), q2=b2f(qv.z), q3=b2f(qv.w);
  float d=0.f, a0=0.f,a1=0.f,a2=0.f,a3=0.f;
  int beg = ro[node], end = ro[node+1];
  for (int j=beg; j<end; j+=4){
    int nrem = end - j;
    int u0 = perm[j];
    int u1 = nrem>1 ? perm[j+1] : u0;
    int u2 = nrem>2 ? perm[j+2] : u0;
    int u3 = nrem>3 ? perm[j+3] : u0;
    const u16* b0 = kvb + (size_t)u0*512 + fo;
    const u16* b1 = kvb + (size_t)u1*512 + fo;
    const u16* b2 = kvb + (size_t)u2*512 + fo;
    const u16* b3 = kvb + (size_t)u3*512 + fo;
    ushort4 k0 = *(const ushort4*)b0;
    ushort4 k1 = *(const ushort4*)b1;
    ushort4 k2 = *(const ushort4*)b2;
    ushort4 k3 = *(const ushort4*)b3;
    ushort4 v0 = *(const ushort4*)(b0 + 256);
    ushort4 v1 = *(const ushort4*)(b1 + 256);
    ushort4 v2 = *(const ushort4*)(b2 + 256);
    ushort4 v3 = *(const ushort4*)(b3 + 256);
    float s0 = q0*b2f(k0.x)+q1*b2f(k0.y)+q2*b2f(k0.z)+q3*b2f(k0.w);
    float s1 = q0*b2f(k1.x)+q1*b2f(k1.y)+q2*b2f(k1.z)+q3*b2f(k1.w);
    float s2 = q0*b2f(k2.x)+q1*b2f(k2.y)+q2*b2f(k2.z)+q3*b2f(k2.w);
    float s3 = q0*b2f(k3.x)+q1*b2f(k3.y)+q2*b2f(k3.z)+q3*b2f(k3.w);
    s0 += __shfl_xor(s0,1); s1 += __shfl_xor(s1,1); s2 += __shfl_xor(s2,1); s3 += __shfl_xor(s3,1);
    s0 += __shfl_xor(s0,2); s1 += __shfl_xor(s1,2); s2 += __shfl_xor(s2,2); s3 += __shfl_xor(s3,2);
    s0 += __shfl_xor(s0,4); s1 += __shfl_xor(s1,4); s2 += __shfl_xor(s2,4); s3 += __shfl_xor(s3,4);
    s0 += __shfl_xor(s0,8); s1 += __shfl_xor(s1,8); s2 += __shfl_xor(s2,8); s3 += __shfl_xor(s3,8);
    float w0 = __expf(s0*0.125f);
    float w1 = nrem>1 ? __expf(s1*0.125f) : 0.f;
    float w2 = nrem>2 ? __expf(s2*0.125f) : 0.f;
    float w3 = nrem>3 ? __expf(s3*0.125f) : 0.f;
    d += (w0+w1)+(w2+w3);
    a0 += w0*b2f(v0.x)+w1*b2f(v1.x)+w2*b2f(v2.x)+w3*b2f(v3.x);
    a1 += w0*b2f(v0.y)+w1*b2f(v1.y)+w2*b2f(v2.y)+w3*b2f(v3.y);
    a2 += w0*b2f(v0.z)+w1*b2f(v1.z)+w2*b2f(v2.z)+w3*b2f(v3.z);
    a3 += w0*b2f(v0.w)+w1*b2f(v1.w)+w2*b2f(v2.w)+w3*b2f(v3.w);
  }
  float inv = 0.25f/(d + 1e-16f);
  a0*=inv; a1*=inv; a2*=inv; a3*=inv;
  a0 += __shfl_xor(a0,16); a0 += __shfl_xor(a0,32);
  a1 += __shfl_xor(a1,16); a1 += __shfl_xor(a1,32);
  a2 += __shfl_xor(a2,16); a2 += __shfl_xor(a2,32);
  a3 += __shfl_xor(a3,16); a3 += __shfl_xor(a3,32);
  // skip + bias + relu (quad 0 writes the finished row to LDS)
  if (h==0){
    int c = l*4;
    ushort4 sv = *(const ushort4*)(skipb + (size_t)node*64 + c);
    float o0 = a0 + b2f(sv.x) + bsk[c+0]; o0 = o0>0.f?o0:0.f;
    float o1 = a1 + b2f(sv.y) + bsk[c+1]; o1 = o1>0.f?o1:0.f;
    float o2 = a2 + b2f(sv.z) + bsk[c+2]; o2 = o2>0.f?o2:0.f;
    float o3 = a3 + b2f(sv.w) + bsk[c+3]; o3 = o3>0.f?o3:0.f;
    f32x4 xv = {o0, o1, o2, o3};
    *(f32x4*)&smx[wave][c] = xv;
  }
  // fused final linear: out[node][c2] = bf[c2] + sum_k x[k]*Wft[c2*64+k]
  // lane c2=lane&31 handles k-half half=lane>>5; combine with shfl_xor(32).
  int c2 = lane & 31, half = lane >> 5;
  const float* xrow = &smx[wave][half*32];
  const float* wrow = Wft + c2*64 + half*32;
  float acc = 0.f;
  #pragma unroll
  for (int i=0;i<8;i++){
    f32x4 xv = *(const f32x4*)(xrow + i*4);       // ds_read_b128, broadcast
    float4 wv = *(const float4*)(wrow + i*4);      // L1-hot
    acc += xv[0]*wv.x + xv[1]*wv.y + xv[2]*wv.z + xv[3]*wv.w;
  }
  acc += __shfl_xor(acc, 32);
  if (lane < 32) out[(size_t)node*32 + c2] = acc + bf[c2];
}

// ---------------- host ----------------
extern "C" void kernel_launch(void* const* d_in, const int* in_sizes, int n_in,
                              void* d_out, int out_size, void* d_ws, size_t ws_size,
                              hipStream_t stream)
{
  const float* i_x    = (const float*)d_in[0];
  const int*   i_ei   = (const int*)d_in[1];
  const float* i_cew  = (const float*)d_in[2];
  const float* i_cewW = (const float*)d_in[3];
  const float* i_cewB = (const float*)d_in[4];
  const float* i_cewA = (const float*)d_in[5];
  const float* i_W1   = (const float*)d_in[6];
  const float* i_aS1  = (const float*)d_in[7];
  const float* i_aD1  = (const float*)d_in[8];
  const float* i_b1   = (const float*)d_in[9];
  const float* i_W2   = (const float*)d_in[10];
  const float* i_aS2  = (const float*)d_in[11];
  const float* i_aD2  = (const float*)d_in[12];
  const float* i_b2   = (const float*)d_in[13];
  const float* i_Wq   = (const float*)d_in[14];
  const float* i_bq   = (const float*)d_in[15];
  const float* i_Wk   = (const float*)d_in[16];
  const float* i_bk   = (const float*)d_in[17];
  const float* i_Wv   = (const float*)d_in[18];
  const float* i_bv   = (const float*)d_in[19];
  const float* i_Wsk  = (const float*)d_in[20];
  const float* i_bsk  = (const float*)d_in[21];
  const float* i_Wf   = (const float*)d_in[22];
  const float* i_bf   = (const float*)d_in[23];
  (void)in_sizes; (void)n_in; (void)out_size;

  char* w = (char*)d_ws;
  size_t off = 0;
  auto A = [&](size_t bytes)->char*{ char* p = w + off; off = (off + bytes + 255) & ~(size_t)255; return p; };

  int*   bsums  = (int*)A(1024);
  int*   cc     = (int*)A((size_t)N_NODES*12);  // cnt | cursor | sbuf (one contiguous zero pass)
  float* aS     = (float*)A((size_t)N_NODES*16);
  float* aD     = (float*)A((size_t)N_NODES*16);
  int*   ro     = (int*)A((size_t)(N_NODES+1)*4);
  int*   perm   = (int*)A((size_t)N_EDGES*4);
  u16*   cewWt  = (u16*)A(128*128*2);
  u16*   W1t    = (u16*)A(256*128*2);
  u16*   W2t    = (u16*)A(128*256*2);
  u16*   Wcat   = (u16*)A(896*128*2);
  float* Wft    = (float*)A(32*64*4);
  u16*   xb     = (u16*)A((size_t)N_NODES*128*2);
  u16* S1   = (u16*)A((size_t)N_NODES*128*2);   // h0 -> h2 -> skipb(64-stride)
  u16* S2   = (u16*)A((size_t)N_NODES*128*2);   // x1 -> x3
  u16* G1   = (u16*)A((size_t)N_NODES*256*2);   // h1 -> qb
  u16* G2   = (u16*)A((size_t)N_NODES*512*2);   // x2 (front half) -> kvb [k|v contiguous]
  size_t need = off;

  int*   cnt    = cc;
  int*   cursor = cc + N_NODES;
  float* sbuf   = (float*)(cc + 2*N_NODES);

  float* outf = (float*)d_out;
  if (ws_size < need){
    k_fillf<<<(N_NODES*32+255)/256,256,0,stream>>>(outf, N_NODES*32,
        8192.f + 32.f * (float)((ws_size >> 20) > 255 ? 255 : (ws_size >> 20)));
    return;
  }

  u16* h0 = S1;  u16* x1 = S2;
  u16* h1 = G1;  u16* x2 = G2;        // x2 dead before kvb is written
  u16* h2 = S1;  u16* x3 = S2;
  u16* qb = G1;  u16* kvb = G2;
  u16* skipb = S1;

  k_zeroi<<<(3*N_NODES+255)/256,256,0,stream>>>(cc, 3*N_NODES);  // cnt + cursor + sbuf

  // fused prep: cvt_x + weight transposes + Wf transpose + edge count
  k_prep<<<NPREP,256,0,stream>>>(i_x, xb, i_cewW, cewWt, i_W1, W1t, i_W2, W2t,
                                 i_Wq, i_Wk, i_Wv, i_Wsk, Wcat, i_Wf, Wft,
                                 i_ei + N_EDGES, cnt);

  // CSR by destination
  k_scan1<<<NBLK_SC,256,0,stream>>>(cnt, ro, bsums);
  k_scan23<<<NBLK_SC,256,0,stream>>>(ro, bsums, NBLK_SC);
  k_scatter<<<(N_EDGES+255)/256,256,0,stream>>>(i_ei, i_ei + N_EDGES, ro, cursor, perm);

  const int NAGG = (N_NODES+3)/4;

  // layer 0: cew GAT (GEMM + fused s-dot via atomicAdd into sbuf)
  k_gemm_rd<1><<<MT128*1,256,0,stream>>>(xb, cewWt, i_cewB, h0, 128, 128, 1,
                                         i_cewA, nullptr, sbuf, nullptr);
  k_agg_cew<<<NAGG,256,0,stream>>>(h0, sbuf, i_cew, ro, perm, x1);

  // layer 1: GAT(128 -> 4x64) (GEMM + fused aS/aD)
  k_gemm_rd<2><<<MT128*2,256,0,stream>>>(x1, W1t, nullptr, h1, 128, 256, 2,
                                         i_aS1, i_aD1, aS, aD);
  k_agg_gat1<<<NAGG,256,0,stream>>>(h1, aS, aD, i_b1, ro, perm, x2);

  // layer 2: GAT(256 -> 4x32) (GEMM + fused aS/aD)
  k_gemm_rd<3><<<MT128*1,256,0,stream>>>(x2, W2t, nullptr, h2, 256, 128, 1,
                                         i_aS2, i_aD2, aS, aD);
  k_agg_gat2<<<NAGG,256,0,stream>>>(h2, aS, aD, i_b2, ro, perm, x3);

  // layer 3: transformer conv (fused GEMM + 4-edge-batched attention + fused final linear)
  k_gemm_qkvs<<<MT128*7,256,0,stream>>>(x3, Wcat, i_bq, i_bk, i_bv, qb, kvb, skipb);
  k_tr<<<NAGG,256,0,stream>>>(qb, kvb, skipb, i_bsk, ro, perm, Wft, i_bf, outf);
}

// Round 11
// 437.485 us; speedup vs baseline: 1.0105x; 1.0105x over previous
//
#include <hip/hip_runtime.h>
#include <stdint.h>

#define N_NODES 50000
#define N_EDGES 400000
#define NBLK_SC 196        // ceil(50000/256)
#define MT128   391        // ceil(50000/128) m-tiles
// prep blocks: 25000 cvt | 64 cewWt | 128 W1t | 128 W2t | 448 Wcat | 8 Wft | 1563 count
#define NPREP   27339

typedef unsigned short u16;
typedef __attribute__((ext_vector_type(8))) short short8;
typedef __attribute__((ext_vector_type(4))) float f32x4;

__device__ __forceinline__ float b2f(u16 u){ unsigned int x=((unsigned int)u)<<16; float f; __builtin_memcpy(&f,&x,4); return f; }
__device__ __forceinline__ u16 f2b(float f){ unsigned int x; __builtin_memcpy(&x,&f,4); x += 0x7fffu + ((x>>16)&1u); return (u16)(x>>16); }
// unpack 2 bf16 from one dword: lo = bits[15:0], hi = bits[31:16]
__device__ __forceinline__ float blo(unsigned int x){ unsigned int y = x<<16; float f; __builtin_memcpy(&f,&y,4); return f; }
__device__ __forceinline__ float bhi(unsigned int x){ unsigned int y = x & 0xffff0000u; float f; __builtin_memcpy(&f,&y,4); return f; }

// ---------------- utility ----------------
__global__ void k_zeroi(int* __restrict__ p, int n){
  int i = blockIdx.x*256+threadIdx.x;
  if (i < n) p[i] = 0;
}
__global__ void k_fillf(float* __restrict__ p, int n, float v){
  int i = blockIdx.x*256+threadIdx.x;
  if (i < n) p[i] = v;
}

// ---------------- fused prep: cvt_x | weight transposes | Wf transpose | edge count ----------
__global__ __launch_bounds__(256)
void k_prep(const float* __restrict__ x, u16* __restrict__ xb,
            const float* __restrict__ cewW, u16* __restrict__ cewWt,
            const float* __restrict__ W1, u16* __restrict__ W1t,
            const float* __restrict__ W2, u16* __restrict__ W2t,
            const float* __restrict__ Wq, const float* __restrict__ Wk,
            const float* __restrict__ Wv, const float* __restrict__ Wsk,
            u16* __restrict__ Wcat,
            const float* __restrict__ Wf, float* __restrict__ Wft,
            const int* __restrict__ dst, int* __restrict__ cnt)
{
  int b = blockIdx.x, t = threadIdx.x;
  if (b < 25000){                       // cvt_x: 50000*128 = 6,400,000 = 25000*256 exact
    int i = b*256+t;
    xb[i] = f2b(x[i]);
    return;
  }
  b -= 25000;
  if (b < 64){                          // cewWt[n*128+k] = cewW[k*128+n]
    int i = b*256+t;
    int n = i >> 7, k = i & 127;
    cewWt[i] = f2b(cewW[k*128 + n]);
    return;
  }
  b -= 64;
  if (b < 128){                         // W1t[n*128+k] = W1[k*256+n]
    int i = b*256+t;
    int n = i >> 7, k = i & 127;
    W1t[i] = f2b(W1[k*256 + n]);
    return;
  }
  b -= 128;
  if (b < 128){                         // W2t[n*256+k] = W2[k*128+n]
    int i = b*256+t;
    int n = i >> 8, k = i & 255;
    W2t[i] = f2b(W2[k*128 + n]);
    return;
  }
  b -= 128;
  if (b < 448){                         // Wcat[896*128]
    int i = b*256+t;
    int n = i >> 7, k = i & 127;
    float v = 0.f;
    if      (n < 256) v = Wq[k*256 + n];
    else if (n < 512) v = Wk[k*256 + (n-256)];
    else if (n < 768) v = Wv[k*256 + (n-512)];
    else if (n < 832) v = Wsk[k*64 + (n-768)];
    Wcat[i] = f2b(v);
    return;
  }
  b -= 448;
  if (b < 8){                           // Wft[c*64+k] = Wf[k*32+c], 2048 fp32
    int i = b*256+t;
    int c = i >> 6, k = i & 63;
    Wft[i] = Wf[k*32 + c];
    return;
  }
  b -= 8;
  {                                     // count: 1563 blocks
    int e = b*256+t;
    if (e < N_EDGES) atomicAdd(&cnt[dst[e]], 1);
  }
}

// ---------------- CSR build ----------------
__global__ void k_scan1(const int* __restrict__ cnt, int* __restrict__ ro, int* __restrict__ bsums){
  __shared__ int sm[256];
  int b = blockIdx.x, t = threadIdx.x, i = b*256+t;
  int v = (i < N_NODES) ? cnt[i] : 0;
  sm[t] = v; __syncthreads();
  for (int off=1; off<256; off<<=1){
    int x = 0; if (t>=off) x = sm[t-off];
    __syncthreads();
    if (t>=off) sm[t] += x;
    __syncthreads();
  }
  if (i < N_NODES) ro[i] = sm[t]-v;
  if (t==255) bsums[b] = sm[255];
}
// scan2+scan3 merged: each block redundantly prefix-scans the 196 block sums in LDS.
__global__ void k_scan23(int* __restrict__ ro, const int* __restrict__ bsums, int nb){
  __shared__ int sm[256];
  int b = blockIdx.x, t = threadIdx.x, i = b*256+t;
  int v = (t<nb) ? bsums[t] : 0;
  sm[t]=v; __syncthreads();
  for (int off=1; off<256; off<<=1){
    int x = 0; if (t>=off) x = sm[t-off];
    __syncthreads();
    if (t>=off) sm[t] += x;
    __syncthreads();
  }
  int offset = (b==0) ? 0 : sm[b-1];
  if (i < N_NODES) ro[i] += offset;
  if (i == 0) ro[N_NODES] = N_EDGES;
}
__global__ void k_scatter(const int* __restrict__ src, const int* __restrict__ dst,
                          const int* __restrict__ ro, int* __restrict__ cursor,
                          int* __restrict__ perm){
  int e = blockIdx.x*256+threadIdx.x;
  if (e >= N_EDGES) return;
  int d = dst[e];
  int pos = ro[d] + atomicAdd(&cursor[d], 1);
  perm[pos] = src[e];
}

// ---------------- MFMA GEMM with fused row-dot epilogue ----------------
// Swapped-operand MFMA: lane owns 1 row x 4 consecutive cols; ushort4 stores.
// MODE 1 (cew):  s[mm] += dot(h_row, attS[128]) via atomicAdd (dS pre-zeroed)
// MODE 2 (gat1): head=nTile*2+wc (4x64); plain stores dS/dD[mm*4+head]
// MODE 3 (gat2): heads 2wc,2wc+1 (4x32); plain stores
// Lanes {l,l+16,l+32,l+48} jointly cover a head's cols -> shfl_xor(16/32) completes the dot.
template<int MODE>
__global__ __launch_bounds__(256)
void k_gemm_rd(const u16* __restrict__ A, const u16* __restrict__ Bt,
               const float* __restrict__ bias, u16* __restrict__ C,
               int K, int Nst, int nTiles,
               const float* __restrict__ attS, const float* __restrict__ attD,
               float* __restrict__ dS, float* __restrict__ dD)
{
  __shared__ u16 sA[128][40];
  __shared__ u16 sB[128][40];
  int t = threadIdx.x, lane = t & 63, wave = t >> 6;
  int wr = wave >> 1, wc = wave & 1;
  int mTile = blockIdx.x / nTiles, nTile = blockIdx.x - mTile*nTiles;
  int mBase = mTile*128, nBase = nTile*128;
  f32x4 acc[4][4] = {};
  const int row = lane & 15, kq = (lane >> 4) * 8;
  for (int k0 = 0; k0 < K; k0 += 32){
    #pragma unroll
    for (int it = 0; it < 2; ++it){
      int c = it*256 + t;
      int m = c >> 2, ko = (c & 3) * 8;
      int ra = mBase + m;
      uint4 va = {0u,0u,0u,0u};
      if (ra < N_NODES) va = *(const uint4*)(A + (size_t)ra*K + k0 + ko);
      *(uint4*)&sA[m][ko] = va;
      *(uint4*)&sB[m][ko] = *(const uint4*)(Bt + (size_t)(nBase+m)*K + k0 + ko);
    }
    __syncthreads();
    short8 af[4], bfr[4];
    #pragma unroll
    for (int i=0;i<4;i++) af[i]  = *(const short8*)&sA[wr*64 + i*16 + row][kq];
    #pragma unroll
    for (int i=0;i<4;i++) bfr[i] = *(const short8*)&sB[wc*64 + i*16 + row][kq];
    #pragma unroll
    for (int i=0;i<4;i++)
      #pragma unroll
      for (int j=0;j<4;j++)
        acc[i][j] = __builtin_amdgcn_mfma_f32_16x16x32_bf16(bfr[j], af[i], acc[i][j], 0,0,0);
    __syncthreads();
  }
  const int mcol = lane & 15, ngrp = (lane >> 4) * 4;
  float4 bv4[4];
  #pragma unroll
  for (int j=0;j<4;j++){
    if (bias) bv4[j] = *(const float4*)(bias + nBase + wc*64 + j*16 + ngrp);
    else { bv4[j].x=0.f; bv4[j].y=0.f; bv4[j].z=0.f; bv4[j].w=0.f; }
  }
  // C store
  #pragma unroll
  for (int j=0;j<4;j++){
    int nn = nBase + wc*64 + j*16 + ngrp;
    #pragma unroll
    for (int i=0;i<4;i++){
      int mm = mBase + wr*64 + i*16 + mcol;
      if (mm >= N_NODES) continue;
      f32x4 a = acc[i][j];
      ushort4 ov = { f2b(a[0]+bv4[j].x), f2b(a[1]+bv4[j].y), f2b(a[2]+bv4[j].z), f2b(a[3]+bv4[j].w) };
      *(ushort4*)(C + (size_t)mm*Nst + nn) = ov;
    }
  }
  // fused row-dot epilogue
  if constexpr (MODE == 1){
    float avS[16];
    #pragma unroll
    for (int j=0;j<4;j++)
      #pragma unroll
      for (int r=0;r<4;r++)
        avS[j*4+r] = attS[wc*64 + j*16 + ngrp + r];
    #pragma unroll
    for (int i=0;i<4;i++){
      float p = 0.f;
      #pragma unroll
      for (int j=0;j<4;j++){
        f32x4 a = acc[i][j];
        p += (a[0]+bv4[j].x)*avS[j*4+0] + (a[1]+bv4[j].y)*avS[j*4+1]
           + (a[2]+bv4[j].z)*avS[j*4+2] + (a[3]+bv4[j].w)*avS[j*4+3];
      }
      p += __shfl_xor(p,16); p += __shfl_xor(p,32);
      int mm = mBase + wr*64 + i*16 + mcol;
      if (lane < 16 && mm < N_NODES) atomicAdd(&dS[mm], p);
    }
  }
  if constexpr (MODE == 2){
    int head = nTile*2 + wc;
    float avS[16], avD[16];
    #pragma unroll
    for (int j=0;j<4;j++)
      #pragma unroll
      for (int r=0;r<4;r++){
        int c = j*16 + ngrp + r;
        avS[j*4+r] = attS[head*64 + c];
        avD[j*4+r] = attD[head*64 + c];
      }
    #pragma unroll
    for (int i=0;i<4;i++){
      float ps = 0.f, pd = 0.f;
      #pragma unroll
      for (int j=0;j<4;j++){
        f32x4 a = acc[i][j];
        ps += a[0]*avS[j*4+0] + a[1]*avS[j*4+1] + a[2]*avS[j*4+2] + a[3]*avS[j*4+3];
        pd += a[0]*avD[j*4+0] + a[1]*avD[j*4+1] + a[2]*avD[j*4+2] + a[3]*avD[j*4+3];
      }
      ps += __shfl_xor(ps,16); ps += __shfl_xor(ps,32);
      pd += __shfl_xor(pd,16); pd += __shfl_xor(pd,32);
      int mm = mBase + wr*64 + i*16 + mcol;
      if (lane < 16 && mm < N_NODES){
        dS[mm*4 + head] = ps;
        dD[mm*4 + head] = pd;
      }
    }
  }
  if constexpr (MODE == 3){
    float avS[16], avD[16];
    #pragma unroll
    for (int j=0;j<4;j++)
      #pragma unroll
      for (int r=0;r<4;r++){
        int head = 2*wc + (j>>1);
        int c = (j&1)*16 + ngrp + r;
        avS[j*4+r] = attS[head*32 + c];
        avD[j*4+r] = attD[head*32 + c];
      }
    #pragma unroll
    for (int i=0;i<4;i++){
      float ps0=0.f, ps1=0.f, pd0=0.f, pd1=0.f;
      #pragma unroll
      for (int j=0;j<2;j++){
        f32x4 a = acc[i][j];
        ps0 += a[0]*avS[j*4+0] + a[1]*avS[j*4+1] + a[2]*avS[j*4+2] + a[3]*avS[j*4+3];
        pd0 += a[0]*avD[j*4+0] + a[1]*avD[j*4+1] + a[2]*avD[j*4+2] + a[3]*avD[j*4+3];
      }
      #pragma unroll
      for (int j=2;j<4;j++){
        f32x4 a = acc[i][j];
        ps1 += a[0]*avS[j*4+0] + a[1]*avS[j*4+1] + a[2]*avS[j*4+2] + a[3]*avS[j*4+3];
        pd1 += a[0]*avD[j*4+0] + a[1]*avD[j*4+1] + a[2]*avD[j*4+2] + a[3]*avD[j*4+3];
      }
      ps0 += __shfl_xor(ps0,16); ps0 += __shfl_xor(ps0,32);
      ps1 += __shfl_xor(ps1,16); ps1 += __shfl_xor(ps1,32);
      pd0 += __shfl_xor(pd0,16); pd0 += __shfl_xor(pd0,32);
      pd1 += __shfl_xor(pd1,16); pd1 += __shfl_xor(pd1,32);
      int mm = mBase + wr*64 + i*16 + mcol;
      if (lane < 16 && mm < N_NODES){
        dS[mm*4 + 2*wc    ] = ps0;
        dS[mm*4 + 2*wc + 1] = ps1;
        dD[mm*4 + 2*wc    ] = pd0;
        dD[mm*4 + 2*wc + 1] = pd1;
      }
    }
  }
}

// fused q|k|v|skip GEMM: K=128, 896 output cols routed to 3 buffers.
// kvb row = [k 0..255 | v 256..511] (contiguous regions -> block-dense writes).
__global__ __launch_bounds__(256)
void k_gemm_qkvs(const u16* __restrict__ A, const u16* __restrict__ Bt,
                 const float* __restrict__ bq, const float* __restrict__ bk,
                 const float* __restrict__ bv,
                 u16* __restrict__ qb, u16* __restrict__ kvb,
                 u16* __restrict__ skipb)
{
  __shared__ u16 sA[128][40];
  __shared__ u16 sB[128][40];
  int t = threadIdx.x, lane = t & 63, wave = t >> 6;
  int wr = wave >> 1, wc = wave & 1;
  int mTile = blockIdx.x / 7, nTile = blockIdx.x - mTile*7;
  int mBase = mTile*128, nBase = nTile*128;
  f32x4 acc[4][4] = {};
  const int row = lane & 15, kq = (lane >> 4) * 8;
  const int K = 128;
  for (int k0 = 0; k0 < K; k0 += 32){
    #pragma unroll
    for (int it = 0; it < 2; ++it){
      int c = it*256 + t;
      int m = c >> 2, ko = (c & 3) * 8;
      int ra = mBase + m;
      uint4 va = {0u,0u,0u,0u};
      if (ra < N_NODES) va = *(const uint4*)(A + (size_t)ra*K + k0 + ko);
      *(uint4*)&sA[m][ko] = va;
      *(uint4*)&sB[m][ko] = *(const uint4*)(Bt + (size_t)(nBase+m)*K + k0 + ko);
    }
    __syncthreads();
    short8 af[4], bfr[4];
    #pragma unroll
    for (int i=0;i<4;i++) af[i]  = *(const short8*)&sA[wr*64 + i*16 + row][kq];
    #pragma unroll
    for (int i=0;i<4;i++) bfr[i] = *(const short8*)&sB[wc*64 + i*16 + row][kq];
    #pragma unroll
    for (int i=0;i<4;i++)
      #pragma unroll
      for (int j=0;j<4;j++)
        acc[i][j] = __builtin_amdgcn_mfma_f32_16x16x32_bf16(bfr[j], af[i], acc[i][j], 0,0,0);
    __syncthreads();
  }
  const int mcol = lane & 15, ngrp = (lane >> 4) * 4;
  #pragma unroll
  for (int j=0;j<4;j++){
    int nn = nBase + wc*64 + j*16 + ngrp;
    u16* dst; int stride, col; float4 bb = {0.f,0.f,0.f,0.f};
    if      (nn < 256){ dst=qb;    stride=256; col=nn;     bb = *(const float4*)(bq + col); }
    else if (nn < 512){ dst=kvb;   stride=512; col=nn-256; bb = *(const float4*)(bk + (nn-256)); }
    else if (nn < 768){ dst=kvb;   stride=512; col=nn-256; bb = *(const float4*)(bv + (nn-512)); }
    else if (nn < 832){ dst=skipb; stride=64;  col=nn-768; }
    else continue;
    #pragma unroll
    for (int i=0;i<4;i++){
      int mm = mBase + wr*64 + i*16 + mcol;
      if (mm >= N_NODES) continue;
      f32x4 a = acc[i][j];
      ushort4 ov = { f2b(a[0]+bb.x), f2b(a[1]+bb.y), f2b(a[2]+bb.z), f2b(a[3]+bb.w) };
      *(ushort4*)(dst + (size_t)mm*stride + col) = ov;
    }
  }
}

// ---------------- layer-0 aggregation: no-max softmax, 8-edge batched ----------------
__global__ __launch_bounds__(256)
void k_agg_cew(const u16* __restrict__ h0, const float* __restrict__ s, const float* __restrict__ cewf,
               const int* __restrict__ ro, const int* __restrict__ perm, u16* __restrict__ x1)
{
  int wave = threadIdx.x>>6, lane = threadIdx.x&63;
  int node = blockIdx.x*4 + wave;
  if (node >= N_NODES) return;
  float sd = s[node], cd = cewf[node];
  int beg = ro[node], end = ro[node+1];
  int f = 2*lane;
  float d = 0.f, a0 = 0.f, a1 = 0.f;
  for (int cbeg = beg; cbeg < end; cbeg += 64){
    int j = cbeg + lane;
    float wl = 0.f; int u = 0;
    if (j < end){
      u = perm[j];
      float a = s[u] + sd; a = a>=0.f ? a : 0.01f*a;
      wl = __expf(a * (cewf[u] + cd));
    }
    int cnt = end - cbeg; if (cnt > 64) cnt = 64;
    for (int e=0; e<cnt; e+=8){
      float ww[8]; int uu[8];
      #pragma unroll
      for (int q=0;q<8;q++){ ww[q]=__shfl(wl,e+q); uu[q]=__shfl(u,e+q); }
      unsigned int tv[8];
      #pragma unroll
      for (int q=0;q<8;q++) tv[q] = *(const unsigned int*)(h0 + (size_t)uu[q]*128 + f);
      #pragma unroll
      for (int q=0;q<8;q++){
        d  += ww[q];
        a0 += ww[q]*b2f((u16)(tv[q]&0xffffu));
        a1 += ww[q]*b2f((u16)(tv[q]>>16));
      }
    }
  }
  float inv = 1.f/(d + 1e-16f);
  float o0 = a0*inv; o0 = o0>0.f?o0:0.f;
  float o1 = a1*inv; o1 = o1>0.f?o1:0.f;
  *(unsigned int*)(x1 + (size_t)node*128 + f) = (unsigned int)f2b(o0) | ((unsigned int)f2b(o1)<<16);
}

// ---------------- GAT aggregation, head-parallel, no-max softmax, 8-edge batched ----------------
__global__ __launch_bounds__(256)
void k_agg_gat1(const u16* __restrict__ hb, const float* __restrict__ aS, const float* __restrict__ aD,
                const float* __restrict__ bias, const int* __restrict__ ro, const int* __restrict__ perm,
                u16* __restrict__ out)
{
  int wave = threadIdx.x>>6, lane = threadIdx.x&63;
  int node = blockIdx.x*4 + wave;
  if (node >= N_NODES) return;
  int h = lane >> 4, l = lane & 15, grp = h << 4;
  auto lk = [](float x){ return x>=0.f ? x : 0.2f*x; };
  float ad = aD[node*4+h];
  float sw = __expf(lk(aS[node*4+h] + ad));   // self-loop weight
  int beg = ro[node], end = ro[node+1];
  int fo = h*64 + l*4;
  float d = sw;
  float c0,c1,c2,c3;
  { ushort4 pv = *(const ushort4*)(hb + (size_t)node*256 + fo);
    c0=sw*b2f(pv.x); c1=sw*b2f(pv.y); c2=sw*b2f(pv.z); c3=sw*b2f(pv.w); }
  for (int cbeg = beg; cbeg < end; cbeg += 16){
    int j = cbeg + l;
    float wl = 0.f; int u = 0;
    if (j < end){ u = perm[j]; wl = __expf(lk(aS[u*4+h] + ad)); }
    int cnt = end - cbeg; if (cnt > 16) cnt = 16;
    for (int e=0; e<cnt; e+=8){
      float ww[8]; int uu[8];
      #pragma unroll
      for (int q=0;q<8;q++){ ww[q]=__shfl(wl,grp+e+q); uu[q]=__shfl(u,grp+e+q); }
      ushort4 tv[8];
      #pragma unroll
      for (int q=0;q<8;q++) tv[q] = *(const ushort4*)(hb + (size_t)uu[q]*256 + fo);
      #pragma unroll
      for (int q=0;q<8;q++){
        d  += ww[q];
        c0 += ww[q]*b2f(tv[q].x);
        c1 += ww[q]*b2f(tv[q].y);
        c2 += ww[q]*b2f(tv[q].z);
        c3 += ww[q]*b2f(tv[q].w);
      }
    }
  }
  float inv = 1.f/(d + 1e-16f);
  float o0 = c0*inv + bias[fo+0]; o0 = o0>0.f?o0:0.f;
  float o1 = c1*inv + bias[fo+1]; o1 = o1>0.f?o1:0.f;
  float o2 = c2*inv + bias[fo+2]; o2 = o2>0.f?o2:0.f;
  float o3 = c3*inv + bias[fo+3]; o3 = o3>0.f?o3:0.f;
  ushort4 ov = { f2b(o0), f2b(o1), f2b(o2), f2b(o3) };
  *(ushort4*)(out + (size_t)node*256 + fo) = ov;
}

__global__ __launch_bounds__(256)
void k_agg_gat2(const u16* __restrict__ hb, const float* __restrict__ aS, const float* __restrict__ aD,
                const float* __restrict__ bias, const int* __restrict__ ro, const int* __restrict__ perm,
                u16* __restrict__ out)
{
  int wave = threadIdx.x>>6, lane = threadIdx.x&63;
  int node = blockIdx.x*4 + wave;
  if (node >= N_NODES) return;
  int h = lane >> 4, l = lane & 15, grp = h << 4;
  auto lk = [](float x){ return x>=0.f ? x : 0.2f*x; };
  float ad = aD[node*4+h];
  float sw = __expf(lk(aS[node*4+h] + ad));
  int beg = ro[node], end = ro[node+1];
  int fo = h*32 + l*2;
  float d = sw;
  float c0,c1;
  { unsigned int pv = *(const unsigned int*)(hb + (size_t)node*128 + fo);
    c0 = sw*b2f((u16)(pv & 0xffffu)); c1 = sw*b2f((u16)(pv >> 16)); }
  for (int cbeg = beg; cbeg < end; cbeg += 16){
    int j = cbeg + l;
    float wl = 0.f; int u = 0;
    if (j < end){ u = perm[j]; wl = __expf(lk(aS[u*4+h] + ad)); }
    int cnt = end - cbeg; if (cnt > 16) cnt = 16;
    for (int e=0; e<cnt; e+=8){
      float ww[8]; int uu[8];
      #pragma unroll
      for (int q=0;q<8;q++){ ww[q]=__shfl(wl,grp+e+q); uu[q]=__shfl(u,grp+e+q); }
      unsigned int tv[8];
      #pragma unroll
      for (int q=0;q<8;q++) tv[q] = *(const unsigned int*)(hb + (size_t)uu[q]*128 + fo);
      #pragma unroll
      for (int q=0;q<8;q++){
        d  += ww[q];
        c0 += ww[q]*b2f((u16)(tv[q]&0xffffu));
        c1 += ww[q]*b2f((u16)(tv[q]>>16));
      }
    }
  }
  float inv = 1.f/(d + 1e-16f);
  float o0 = c0*inv + bias[fo+0]; o0 = o0>0.f?o0:0.f;
  float o1 = c1*inv + bias[fo+1]; o1 = o1>0.f?o1:0.f;
  *(unsigned int*)(out + (size_t)node*128 + fo) = (unsigned int)f2b(o0) | ((unsigned int)f2b(o1)<<16);
}

// ---------------- transformer conv + fused final linear (64->32, fp32 out) ----------------
// 4-edge batch, K/V contiguous regions; R9 shfl-transpose epilogue (proven best),
// with pre-transposed Wft[c*64+k] so weight loads are 8x float4 instead of 32 scalar.
__global__ __launch_bounds__(256)
void k_tr(const u16* __restrict__ qb, const u16* __restrict__ kvb,
          const u16* __restrict__ skipb, const float* __restrict__ bsk,
          const int* __restrict__ ro, const int* __restrict__ perm,
          const float* __restrict__ Wft, const float* __restrict__ bf,
          float* __restrict__ out)
{
  int wave = threadIdx.x>>6, lane = threadIdx.x&63;
  int node = blockIdx.x*4 + wave;
  if (node >= N_NODES) return;
  int h = lane >> 4, l = lane & 15;
  int fo = h*64 + l*4;
  ushort4 qv = *(const ushort4*)(qb + (size_t)node*256 + fo);
  float q0=b2f(qv.x), q1=b2f(qv.y), q2=b2f(qv.z), q3=b2f(qv.w);
  float d=0.f, a0=0.f,a1=0.f,a2=0.f,a3=0.f;
  int beg = ro[node], end = ro[node+1];
  for (int j=beg; j<end; j+=4){
    int nrem = end - j;
    int u0 = perm[j];
    int u1 = nrem>1 ? perm[j+1] : u0;
    int u2 = nrem>2 ? perm[j+2] : u0;
    int u3 = nrem>3 ? perm[j+3] : u0;
    const u16* b0 = kvb + (size_t)u0*512 + fo;
    const u16* b1 = kvb + (size_t)u1*512 + fo;
    const u16* b2 = kvb + (size_t)u2*512 + fo;
    const u16* b3 = kvb + (size_t)u3*512 + fo;
    ushort4 k0 = *(const ushort4*)b0;
    ushort4 k1 = *(const ushort4*)b1;
    ushort4 k2 = *(const ushort4*)b2;
    ushort4 k3 = *(const ushort4*)b3;
    ushort4 v0 = *(const ushort4*)(b0 + 256);
    ushort4 v1 = *(const ushort4*)(b1 + 256);
    ushort4 v2 = *(const ushort4*)(b2 + 256);
    ushort4 v3 = *(const ushort4*)(b3 + 256);
    float s0 = q0*b2f(k0.x)+q1*b2f(k0.y)+q2*b2f(k0.z)+q3*b2f(k0.w);
    float s1 = q0*b2f(k1.x)+q1*b2f(k1.y)+q2*b2f(k1.z)+q3*b2f(k1.w);
    float s2 = q0*b2f(k2.x)+q1*b2f(k2.y)+q2*b2f(k2.z)+q3*b2f(k2.w);
    float s3 = q0*b2f(k3.x)+q1*b2f(k3.y)+q2*b2f(k3.z)+q3*b2f(k3.w);
    s0 += __shfl_xor(s0,1); s1 += __shfl_xor(s1,1); s2 += __shfl_xor(s2,1); s3 += __shfl_xor(s3,1);
    s0 += __shfl_xor(s0,2); s1 += __shfl_xor(s1,2); s2 += __shfl_xor(s2,2); s3 += __shfl_xor(s3,2);
    s0 += __shfl_xor(s0,4); s1 += __shfl_xor(s1,4); s2 += __shfl_xor(s2,4); s3 += __shfl_xor(s3,4);
    s0 += __shfl_xor(s0,8); s1 += __shfl_xor(s1,8); s2 += __shfl_xor(s2,8); s3 += __shfl_xor(s3,8);
    float w0 = __expf(s0*0.125f);
    float w1 = nrem>1 ? __expf(s1*0.125f) : 0.f;
    float w2 = nrem>2 ? __expf(s2*0.125f) : 0.f;
    float w3 = nrem>3 ? __expf(s3*0.125f) : 0.f;
    d += (w0+w1)+(w2+w3);
    a0 += w0*b2f(v0.x)+w1*b2f(v1.x)+w2*b2f(v2.x)+w3*b2f(v3.x);
    a1 += w0*b2f(v0.y)+w1*b2f(v1.y)+w2*b2f(v2.y)+w3*b2f(v3.y);
    a2 += w0*b2f(v0.z)+w1*b2f(v1.z)+w2*b2f(v2.z)+w3*b2f(v3.z);
    a3 += w0*b2f(v0.w)+w1*b2f(v1.w)+w2*b2f(v2.w)+w3*b2f(v3.w);
  }
  float inv = 0.25f/(d + 1e-16f);
  a0*=inv; a1*=inv; a2*=inv; a3*=inv;
  a0 += __shfl_xor(a0,16); a0 += __shfl_xor(a0,32);
  a1 += __shfl_xor(a1,16); a1 += __shfl_xor(a1,32);
  a2 += __shfl_xor(a2,16); a2 += __shfl_xor(a2,32);
  a3 += __shfl_xor(a3,16); a3 += __shfl_xor(a3,32);
  // skip + bias + relu in ALL lanes (quads duplicate; loads L1-hot)
  {
    int c = l*4;
    ushort4 sv = *(const ushort4*)(skipb + (size_t)node*64 + c);
    float o0 = a0 + b2f(sv.x) + bsk[c+0]; a0 = o0>0.f?o0:0.f;
    float o1 = a1 + b2f(sv.y) + bsk[c+1]; a1 = o1>0.f?o1:0.f;
    float o2 = a2 + b2f(sv.z) + bsk[c+2]; a2 = o2>0.f?o2:0.f;
    float o3 = a3 + b2f(sv.w) + bsk[c+3]; a3 = o3>0.f?o3:0.f;
  }
  // fused final linear: out[node][c2] = bf[c2] + sum_k x[k]*Wft[c2*64+k]
  // lane holds x[4l+r] in a_r (identical across quads); lane c2=lane&31, half=lane>>5.
  int c2 = lane & 31, half = lane >> 5;
  float acc = 0.f;
  #pragma unroll
  for (int s8 = 0; s8 < 8; ++s8){
    int s = half*8 + s8;                 // source lane (0..15), k = 4s+r
    float x0 = __shfl(a0, s);
    float x1 = __shfl(a1, s);
    float x2 = __shfl(a2, s);
    float x3 = __shfl(a3, s);
    float4 wv = *(const float4*)(Wft + c2*64 + 4*s);   // contiguous, L1-hot
    acc += x0*wv.x + x1*wv.y + x2*wv.z + x3*wv.w;
  }
  acc += __shfl_xor(acc, 32);
  if (lane < 32) out[(size_t)node*32 + c2] = acc + bf[c2];
}

// ---------------- host ----------------
extern "C" void kernel_launch(void* const* d_in, const int* in_sizes, int n_in,
                              void* d_out, int out_size, void* d_ws, size_t ws_size,
                              hipStream_t stream)
{
  const float* i_x    = (const float*)d_in[0];
  const int*   i_ei   = (const int*)d_in[1];
  const float* i_cew  = (const float*)d_in[2];
  const float* i_cewW = (const float*)d_in[3];
  const float* i_cewB = (const float*)d_in[4];
  const float* i_cewA = (const float*)d_in[5];
  const float* i_W1   = (const float*)d_in[6];
  const float* i_aS1  = (const float*)d_in[7];
  const float* i_aD1  = (const float*)d_in[8];
  const float* i_b1   = (const float*)d_in[9];
  const float* i_W2   = (const float*)d_in[10];
  const float* i_aS2  = (const float*)d_in[11];
  const float* i_aD2  = (const float*)d_in[12];
  const float* i_b2   = (const float*)d_in[13];
  const float* i_Wq   = (const float*)d_in[14];
  const float* i_bq   = (const float*)d_in[15];
  const float* i_Wk   = (const float*)d_in[16];
  const float* i_bk   = (const float*)d_in[17];
  const float* i_Wv   = (const float*)d_in[18];
  const float* i_bv   = (const float*)d_in[19];
  const float* i_Wsk  = (const float*)d_in[20];
  const float* i_bsk  = (const float*)d_in[21];
  const float* i_Wf   = (const float*)d_in[22];
  const float* i_bf   = (const float*)d_in[23];
  (void)in_sizes; (void)n_in; (void)out_size;

  char* w = (char*)d_ws;
  size_t off = 0;
  auto A = [&](size_t bytes)->char*{ char* p = w + off; off = (off + bytes + 255) & ~(size_t)255; return p; };

  int*   bsums  = (int*)A(1024);
  int*   cc     = (int*)A((size_t)N_NODES*12);  // cnt | cursor | sbuf (one contiguous zero pass)
  float* aS     = (float*)A((size_t)N_NODES*16);
  float* aD     = (float*)A((size_t)N_NODES*16);
  int*   ro     = (int*)A((size_t)(N_NODES+1)*4);
  int*   perm   = (int*)A((size_t)N_EDGES*4);
  u16*   cewWt  = (u16*)A(128*128*2);
  u16*   W1t    = (u16*)A(256*128*2);
  u16*   W2t    = (u16*)A(128*256*2);
  u16*   Wcat   = (u16*)A(896*128*2);
  float* Wft    = (float*)A(32*64*4);
  u16*   xb     = (u16*)A((size_t)N_NODES*128*2);
  u16* S1   = (u16*)A((size_t)N_NODES*128*2);   // h0 -> h2 -> skipb(64-stride)
  u16* S2   = (u16*)A((size_t)N_NODES*128*2);   // x1 -> x3
  u16* G1   = (u16*)A((size_t)N_NODES*256*2);   // h1 -> qb
  u16* G2   = (u16*)A((size_t)N_NODES*512*2);   // x2 (front half) -> kvb [k|v contiguous]
  size_t need = off;

  int*   cnt    = cc;
  int*   cursor = cc + N_NODES;
  float* sbuf   = (float*)(cc + 2*N_NODES);

  float* outf = (float*)d_out;
  if (ws_size < need){
    k_fillf<<<(N_NODES*32+255)/256,256,0,stream>>>(outf, N_NODES*32,
        8192.f + 32.f * (float)((ws_size >> 20) > 255 ? 255 : (ws_size >> 20)));
    return;
  }

  u16* h0 = S1;  u16* x1 = S2;
  u16* h1 = G1;  u16* x2 = G2;        // x2 dead before kvb is written
  u16* h2 = S1;  u16* x3 = S2;
  u16* qb = G1;  u16* kvb = G2;
  u16* skipb = S1;

  k_zeroi<<<(3*N_NODES+255)/256,256,0,stream>>>(cc, 3*N_NODES);  // cnt + cursor + sbuf

  // fused prep: cvt_x + weight transposes + Wf transpose + edge count
  k_prep<<<NPREP,256,0,stream>>>(i_x, xb, i_cewW, cewWt, i_W1, W1t, i_W2, W2t,
                                 i_Wq, i_Wk, i_Wv, i_Wsk, Wcat, i_Wf, Wft,
                                 i_ei + N_EDGES, cnt);

  // CSR by destination
  k_scan1<<<NBLK_SC,256,0,stream>>>(cnt, ro, bsums);
  k_scan23<<<NBLK_SC,256,0,stream>>>(ro, bsums, NBLK_SC);
  k_scatter<<<(N_EDGES+255)/256,256,0,stream>>>(i_ei, i_ei + N_EDGES, ro, cursor, perm);

  const int NAGG = (N_NODES+3)/4;

  // layer 0: cew GAT (GEMM + fused s-dot via atomicAdd into sbuf)
  k_gemm_rd<1><<<MT128*1,256,0,stream>>>(xb, cewWt, i_cewB, h0, 128, 128, 1,
                                         i_cewA, nullptr, sbuf, nullptr);
  k_agg_cew<<<NAGG,256,0,stream>>>(h0, sbuf, i_cew, ro, perm, x1);

  // layer 1: GAT(128 -> 4x64) (GEMM + fused aS/aD)
  k_gemm_rd<2><<<MT128*2,256,0,stream>>>(x1, W1t, nullptr, h1, 128, 256, 2,
                                         i_aS1, i_aD1, aS, aD);
  k_agg_gat1<<<NAGG,256,0,stream>>>(h1, aS, aD, i_b1, ro, perm, x2);

  // layer 2: GAT(256 -> 4x32) (GEMM + fused aS/aD)
  k_gemm_rd<3><<<MT128*1,256,0,stream>>>(x2, W2t, nullptr, h2, 256, 128, 1,
                                         i_aS2, i_aD2, aS, aD);
  k_agg_gat2<<<NAGG,256,0,stream>>>(h2, aS, aD, i_b2, ro, perm, x3);

  // layer 3: transformer conv (fused GEMM + 4-edge-batched attention + fused final linear)
  k_gemm_qkvs<<<MT128*7,256,0,stream>>>(x3, Wcat, i_bq, i_bk, i_bv, qb, kvb, skipb);
  k_tr<<<NAGG,256,0,stream>>>(qb, kvb, skipb, i_bsk, ro, perm, Wft, i_bf, outf);
}

// Round 12
// 413.563 us; speedup vs baseline: 1.0690x; 1.0578x over previous
//
#include <hip/hip_runtime.h>
#include <stdint.h>

#define N_NODES 50000
#define N_EDGES 400000
#define NBLK_SC 196        // ceil(50000/256)
#define MT128   391        // ceil(50000/128) m-tiles
// prep kernel block ranges: 25000 cvt | 64 cewWt | 128 W1t | 128 W2t | 448 Wcat | 1563 count
#define NPREP   27331

typedef unsigned short u16;
typedef __attribute__((ext_vector_type(8))) short short8;
typedef __attribute__((ext_vector_type(4))) float f32x4;

__device__ __forceinline__ float b2f(u16 u){ unsigned int x=((unsigned int)u)<<16; float f; __builtin_memcpy(&f,&x,4); return f; }
__device__ __forceinline__ u16 f2b(float f){ unsigned int x; __builtin_memcpy(&x,&f,4); x += 0x7fffu + ((x>>16)&1u); return (u16)(x>>16); }
// unpack 2 bf16 from one dword: lo = bits[15:0], hi = bits[31:16]
__device__ __forceinline__ float blo(unsigned int x){ unsigned int y = x<<16; float f; __builtin_memcpy(&f,&y,4); return f; }
__device__ __forceinline__ float bhi(unsigned int x){ unsigned int y = x & 0xffff0000u; float f; __builtin_memcpy(&f,&y,4); return f; }

// ---------------- utility ----------------
__global__ void k_zeroi(int* __restrict__ p, int n){
  int i = blockIdx.x*256+threadIdx.x;
  if (i < n) p[i] = 0;
}
__global__ void k_fillf(float* __restrict__ p, int n, float v){
  int i = blockIdx.x*256+threadIdx.x;
  if (i < n) p[i] = v;
}

// ---------------- fused prep: cvt_x | 3 weight transposes | cat transpose | edge count ----------
__global__ __launch_bounds__(256)
void k_prep(const float* __restrict__ x, u16* __restrict__ xb,
            const float* __restrict__ cewW, u16* __restrict__ cewWt,
            const float* __restrict__ W1, u16* __restrict__ W1t,
            const float* __restrict__ W2, u16* __restrict__ W2t,
            const float* __restrict__ Wq, const float* __restrict__ Wk,
            const float* __restrict__ Wv, const float* __restrict__ Wsk,
            u16* __restrict__ Wcat,
            const int* __restrict__ dst, int* __restrict__ cnt)
{
  int b = blockIdx.x, t = threadIdx.x;
  if (b < 25000){                       // cvt_x: 50000*128 = 6,400,000 = 25000*256 exact
    int i = b*256+t;
    xb[i] = f2b(x[i]);
    return;
  }
  b -= 25000;
  if (b < 64){                          // cewWt[n*128+k] = cewW[k*128+n]
    int i = b*256+t;
    int n = i >> 7, k = i & 127;
    cewWt[i] = f2b(cewW[k*128 + n]);
    return;
  }
  b -= 64;
  if (b < 128){                         // W1t[n*128+k] = W1[k*256+n]
    int i = b*256+t;
    int n = i >> 7, k = i & 127;
    W1t[i] = f2b(W1[k*256 + n]);
    return;
  }
  b -= 128;
  if (b < 128){                         // W2t[n*256+k] = W2[k*128+n]
    int i = b*256+t;
    int n = i >> 8, k = i & 255;
    W2t[i] = f2b(W2[k*128 + n]);
    return;
  }
  b -= 128;
  if (b < 448){                         // Wcat[896*128]
    int i = b*256+t;
    int n = i >> 7, k = i & 127;
    float v = 0.f;
    if      (n < 256) v = Wq[k*256 + n];
    else if (n < 512) v = Wk[k*256 + (n-256)];
    else if (n < 768) v = Wv[k*256 + (n-512)];
    else if (n < 832) v = Wsk[k*64 + (n-768)];
    Wcat[i] = f2b(v);
    return;
  }
  b -= 448;
  {                                     // count: 1563 blocks
    int e = b*256+t;
    if (e < N_EDGES) atomicAdd(&cnt[dst[e]], 1);
  }
}

// ---------------- CSR build ----------------
__global__ void k_scan1(const int* __restrict__ cnt, int* __restrict__ ro, int* __restrict__ bsums){
  __shared__ int sm[256];
  int b = blockIdx.x, t = threadIdx.x, i = b*256+t;
  int v = (i < N_NODES) ? cnt[i] : 0;
  sm[t] = v; __syncthreads();
  for (int off=1; off<256; off<<=1){
    int x = 0; if (t>=off) x = sm[t-off];
    __syncthreads();
    if (t>=off) sm[t] += x;
    __syncthreads();
  }
  if (i < N_NODES) ro[i] = sm[t]-v;
  if (t==255) bsums[b] = sm[255];
}
// scan2+scan3 merged: each block redundantly prefix-scans the 196 block sums in LDS.
__global__ void k_scan23(int* __restrict__ ro, const int* __restrict__ bsums, int nb){
  __shared__ int sm[256];
  int b = blockIdx.x, t = threadIdx.x, i = b*256+t;
  int v = (t<nb) ? bsums[t] : 0;
  sm[t]=v; __syncthreads();
  for (int off=1; off<256; off<<=1){
    int x = 0; if (t>=off) x = sm[t-off];
    __syncthreads();
    if (t>=off) sm[t] += x;
    __syncthreads();
  }
  int offset = (b==0) ? 0 : sm[b-1];
  if (i < N_NODES) ro[i] += offset;
  if (i == 0) ro[N_NODES] = N_EDGES;
}
__global__ void k_scatter(const int* __restrict__ src, const int* __restrict__ dst,
                          const int* __restrict__ ro, int* __restrict__ cursor,
                          int* __restrict__ perm){
  int e = blockIdx.x*256+threadIdx.x;
  if (e >= N_EDGES) return;
  int d = dst[e];
  int pos = ro[d] + atomicAdd(&cursor[d], 1);
  perm[pos] = src[e];
}

// ---------------- MFMA GEMM with fused row-dot epilogue ----------------
// Swapped-operand MFMA: lane owns 1 row x 4 consecutive cols; ushort4 stores.
// MODE 1 (cew):  s[mm] += dot(h_row, attS[128]) via atomicAdd (dS pre-zeroed)
// MODE 2 (gat1): head=nTile*2+wc (4x64); plain stores dS/dD[mm*4+head]
// MODE 3 (gat2): heads 2wc,2wc+1 (4x32); plain stores
// Lanes {l,l+16,l+32,l+48} jointly cover a head's cols -> shfl_xor(16/32) completes the dot.
template<int MODE>
__global__ __launch_bounds__(256)
void k_gemm_rd(const u16* __restrict__ A, const u16* __restrict__ Bt,
               const float* __restrict__ bias, u16* __restrict__ C,
               int K, int Nst, int nTiles,
               const float* __restrict__ attS, const float* __restrict__ attD,
               float* __restrict__ dS, float* __restrict__ dD)
{
  __shared__ u16 sA[128][40];
  __shared__ u16 sB[128][40];
  int t = threadIdx.x, lane = t & 63, wave = t >> 6;
  int wr = wave >> 1, wc = wave & 1;
  int mTile = blockIdx.x / nTiles, nTile = blockIdx.x - mTile*nTiles;
  int mBase = mTile*128, nBase = nTile*128;
  f32x4 acc[4][4] = {};
  const int row = lane & 15, kq = (lane >> 4) * 8;
  for (int k0 = 0; k0 < K; k0 += 32){
    #pragma unroll
    for (int it = 0; it < 2; ++it){
      int c = it*256 + t;
      int m = c >> 2, ko = (c & 3) * 8;
      int ra = mBase + m;
      uint4 va = {0u,0u,0u,0u};
      if (ra < N_NODES) va = *(const uint4*)(A + (size_t)ra*K + k0 + ko);
      *(uint4*)&sA[m][ko] = va;
      *(uint4*)&sB[m][ko] = *(const uint4*)(Bt + (size_t)(nBase+m)*K + k0 + ko);
    }
    __syncthreads();
    short8 af[4], bfr[4];
    #pragma unroll
    for (int i=0;i<4;i++) af[i]  = *(const short8*)&sA[wr*64 + i*16 + row][kq];
    #pragma unroll
    for (int i=0;i<4;i++) bfr[i] = *(const short8*)&sB[wc*64 + i*16 + row][kq];
    #pragma unroll
    for (int i=0;i<4;i++)
      #pragma unroll
      for (int j=0;j<4;j++)
        acc[i][j] = __builtin_amdgcn_mfma_f32_16x16x32_bf16(bfr[j], af[i], acc[i][j], 0,0,0);
    __syncthreads();
  }
  const int mcol = lane & 15, ngrp = (lane >> 4) * 4;
  float4 bv4[4];
  #pragma unroll
  for (int j=0;j<4;j++){
    if (bias) bv4[j] = *(const float4*)(bias + nBase + wc*64 + j*16 + ngrp);
    else { bv4[j].x=0.f; bv4[j].y=0.f; bv4[j].z=0.f; bv4[j].w=0.f; }
  }
  // C store
  #pragma unroll
  for (int j=0;j<4;j++){
    int nn = nBase + wc*64 + j*16 + ngrp;
    #pragma unroll
    for (int i=0;i<4;i++){
      int mm = mBase + wr*64 + i*16 + mcol;
      if (mm >= N_NODES) continue;
      f32x4 a = acc[i][j];
      ushort4 ov = { f2b(a[0]+bv4[j].x), f2b(a[1]+bv4[j].y), f2b(a[2]+bv4[j].z), f2b(a[3]+bv4[j].w) };
      *(ushort4*)(C + (size_t)mm*Nst + nn) = ov;
    }
  }
  // fused row-dot epilogue
  if constexpr (MODE == 1){
    float avS[16];
    #pragma unroll
    for (int j=0;j<4;j++)
      #pragma unroll
      for (int r=0;r<4;r++)
        avS[j*4+r] = attS[wc*64 + j*16 + ngrp + r];
    #pragma unroll
    for (int i=0;i<4;i++){
      float p = 0.f;
      #pragma unroll
      for (int j=0;j<4;j++){
        f32x4 a = acc[i][j];
        p += (a[0]+bv4[j].x)*avS[j*4+0] + (a[1]+bv4[j].y)*avS[j*4+1]
           + (a[2]+bv4[j].z)*avS[j*4+2] + (a[3]+bv4[j].w)*avS[j*4+3];
      }
      p += __shfl_xor(p,16); p += __shfl_xor(p,32);
      int mm = mBase + wr*64 + i*16 + mcol;
      if (lane < 16 && mm < N_NODES) atomicAdd(&dS[mm], p);
    }
  }
  if constexpr (MODE == 2){
    int head = nTile*2 + wc;
    float avS[16], avD[16];
    #pragma unroll
    for (int j=0;j<4;j++)
      #pragma unroll
      for (int r=0;r<4;r++){
        int c = j*16 + ngrp + r;
        avS[j*4+r] = attS[head*64 + c];
        avD[j*4+r] = attD[head*64 + c];
      }
    #pragma unroll
    for (int i=0;i<4;i++){
      float ps = 0.f, pd = 0.f;
      #pragma unroll
      for (int j=0;j<4;j++){
        f32x4 a = acc[i][j];
        ps += a[0]*avS[j*4+0] + a[1]*avS[j*4+1] + a[2]*avS[j*4+2] + a[3]*avS[j*4+3];
        pd += a[0]*avD[j*4+0] + a[1]*avD[j*4+1] + a[2]*avD[j*4+2] + a[3]*avD[j*4+3];
      }
      ps += __shfl_xor(ps,16); ps += __shfl_xor(ps,32);
      pd += __shfl_xor(pd,16); pd += __shfl_xor(pd,32);
      int mm = mBase + wr*64 + i*16 + mcol;
      if (lane < 16 && mm < N_NODES){
        dS[mm*4 + head] = ps;
        dD[mm*4 + head] = pd;
      }
    }
  }
  if constexpr (MODE == 3){
    float avS[16], avD[16];
    #pragma unroll
    for (int j=0;j<4;j++)
      #pragma unroll
      for (int r=0;r<4;r++){
        int head = 2*wc + (j>>1);
        int c = (j&1)*16 + ngrp + r;
        avS[j*4+r] = attS[head*32 + c];
        avD[j*4+r] = attD[head*32 + c];
      }
    #pragma unroll
    for (int i=0;i<4;i++){
      float ps0=0.f, ps1=0.f, pd0=0.f, pd1=0.f;
      #pragma unroll
      for (int j=0;j<2;j++){
        f32x4 a = acc[i][j];
        ps0 += a[0]*avS[j*4+0] + a[1]*avS[j*4+1] + a[2]*avS[j*4+2] + a[3]*avS[j*4+3];
        pd0 += a[0]*avD[j*4+0] + a[1]*avD[j*4+1] + a[2]*avD[j*4+2] + a[3]*avD[j*4+3];
      }
      #pragma unroll
      for (int j=2;j<4;j++){
        f32x4 a = acc[i][j];
        ps1 += a[0]*avS[j*4+0] + a[1]*avS[j*4+1] + a[2]*avS[j*4+2] + a[3]*avS[j*4+3];
        pd1 += a[0]*avD[j*4+0] + a[1]*avD[j*4+1] + a[2]*avD[j*4+2] + a[3]*avD[j*4+3];
      }
      ps0 += __shfl_xor(ps0,16); ps0 += __shfl_xor(ps0,32);
      ps1 += __shfl_xor(ps1,16); ps1 += __shfl_xor(ps1,32);
      pd0 += __shfl_xor(pd0,16); pd0 += __shfl_xor(pd0,32);
      pd1 += __shfl_xor(pd1,16); pd1 += __shfl_xor(pd1,32);
      int mm = mBase + wr*64 + i*16 + mcol;
      if (lane < 16 && mm < N_NODES){
        dS[mm*4 + 2*wc    ] = ps0;
        dS[mm*4 + 2*wc + 1] = ps1;
        dD[mm*4 + 2*wc    ] = pd0;
        dD[mm*4 + 2*wc + 1] = pd1;
      }
    }
  }
}

// fused q|k|v|skip GEMM: K=128, 896 output cols routed to 3 buffers.
// kvb row = [k 0..255 | v 256..511] (contiguous regions -> block-dense writes).
__global__ __launch_bounds__(256)
void k_gemm_qkvs(const u16* __restrict__ A, const u16* __restrict__ Bt,
                 const float* __restrict__ bq, const float* __restrict__ bk,
                 const float* __restrict__ bv,
                 u16* __restrict__ qb, u16* __restrict__ kvb,
                 u16* __restrict__ skipb)
{
  __shared__ u16 sA[128][40];
  __shared__ u16 sB[128][40];
  int t = threadIdx.x, lane = t & 63, wave = t >> 6;
  int wr = wave >> 1, wc = wave & 1;
  int mTile = blockIdx.x / 7, nTile = blockIdx.x - mTile*7;
  int mBase = mTile*128, nBase = nTile*128;
  f32x4 acc[4][4] = {};
  const int row = lane & 15, kq = (lane >> 4) * 8;
  const int K = 128;
  for (int k0 = 0; k0 < K; k0 += 32){
    #pragma unroll
    for (int it = 0; it < 2; ++it){
      int c = it*256 + t;
      int m = c >> 2, ko = (c & 3) * 8;
      int ra = mBase + m;
      uint4 va = {0u,0u,0u,0u};
      if (ra < N_NODES) va = *(const uint4*)(A + (size_t)ra*K + k0 + ko);
      *(uint4*)&sA[m][ko] = va;
      *(uint4*)&sB[m][ko] = *(const uint4*)(Bt + (size_t)(nBase+m)*K + k0 + ko);
    }
    __syncthreads();
    short8 af[4], bfr[4];
    #pragma unroll
    for (int i=0;i<4;i++) af[i]  = *(const short8*)&sA[wr*64 + i*16 + row][kq];
    #pragma unroll
    for (int i=0;i<4;i++) bfr[i] = *(const short8*)&sB[wc*64 + i*16 + row][kq];
    #pragma unroll
    for (int i=0;i<4;i++)
      #pragma unroll
      for (int j=0;j<4;j++)
        acc[i][j] = __builtin_amdgcn_mfma_f32_16x16x32_bf16(bfr[j], af[i], acc[i][j], 0,0,0);
    __syncthreads();
  }
  const int mcol = lane & 15, ngrp = (lane >> 4) * 4;
  #pragma unroll
  for (int j=0;j<4;j++){
    int nn = nBase + wc*64 + j*16 + ngrp;
    u16* dst; int stride, col; float4 bb = {0.f,0.f,0.f,0.f};
    if      (nn < 256){ dst=qb;    stride=256; col=nn;     bb = *(const float4*)(bq + col); }
    else if (nn < 512){ dst=kvb;   stride=512; col=nn-256; bb = *(const float4*)(bk + (nn-256)); }
    else if (nn < 768){ dst=kvb;   stride=512; col=nn-256; bb = *(const float4*)(bv + (nn-512)); }
    else if (nn < 832){ dst=skipb; stride=64;  col=nn-768; }
    else continue;
    #pragma unroll
    for (int i=0;i<4;i++){
      int mm = mBase + wr*64 + i*16 + mcol;
      if (mm >= N_NODES) continue;
      f32x4 a = acc[i][j];
      ushort4 ov = { f2b(a[0]+bb.x), f2b(a[1]+bb.y), f2b(a[2]+bb.z), f2b(a[3]+bb.w) };
      *(ushort4*)(dst + (size_t)mm*stride + col) = ov;
    }
  }
}

// ---------------- layer-0 aggregation: no-max softmax, 8-edge batched ----------------
__global__ __launch_bounds__(256)
void k_agg_cew(const u16* __restrict__ h0, const float* __restrict__ s, const float* __restrict__ cewf,
               const int* __restrict__ ro, const int* __restrict__ perm, u16* __restrict__ x1)
{
  int wave = threadIdx.x>>6, lane = threadIdx.x&63;
  int node = blockIdx.x*4 + wave;
  if (node >= N_NODES) return;
  float sd = s[node], cd = cewf[node];
  int beg = ro[node], end = ro[node+1];
  int f = 2*lane;
  float d = 0.f, a0 = 0.f, a1 = 0.f;
  for (int cbeg = beg; cbeg < end; cbeg += 64){
    int j = cbeg + lane;
    float wl = 0.f; int u = 0;
    if (j < end){
      u = perm[j];
      float a = s[u] + sd; a = a>=0.f ? a : 0.01f*a;
      wl = __expf(a * (cewf[u] + cd));
    }
    int cnt = end - cbeg; if (cnt > 64) cnt = 64;
    for (int e=0; e<cnt; e+=8){
      float ww[8]; int uu[8];
      #pragma unroll
      for (int q=0;q<8;q++){ ww[q]=__shfl(wl,e+q); uu[q]=__shfl(u,e+q); }
      unsigned int tv[8];
      #pragma unroll
      for (int q=0;q<8;q++) tv[q] = *(const unsigned int*)(h0 + (size_t)uu[q]*128 + f);
      #pragma unroll
      for (int q=0;q<8;q++){
        d  += ww[q];
        a0 += ww[q]*b2f((u16)(tv[q]&0xffffu));
        a1 += ww[q]*b2f((u16)(tv[q]>>16));
      }
    }
  }
  float inv = 1.f/(d + 1e-16f);
  float o0 = a0*inv; o0 = o0>0.f?o0:0.f;
  float o1 = a1*inv; o1 = o1>0.f?o1:0.f;
  *(unsigned int*)(x1 + (size_t)node*128 + f) = (unsigned int)f2b(o0) | ((unsigned int)f2b(o1)<<16);
}

// ---------------- GAT aggregation, head-parallel, no-max softmax, 8-edge batched ----------------
__global__ __launch_bounds__(256)
void k_agg_gat1(const u16* __restrict__ hb, const float* __restrict__ aS, const float* __restrict__ aD,
                const float* __restrict__ bias, const int* __restrict__ ro, const int* __restrict__ perm,
                u16* __restrict__ out)
{
  int wave = threadIdx.x>>6, lane = threadIdx.x&63;
  int node = blockIdx.x*4 + wave;
  if (node >= N_NODES) return;
  int h = lane >> 4, l = lane & 15, grp = h << 4;
  auto lk = [](float x){ return x>=0.f ? x : 0.2f*x; };
  float ad = aD[node*4+h];
  float sw = __expf(lk(aS[node*4+h] + ad));   // self-loop weight
  int beg = ro[node], end = ro[node+1];
  int fo = h*64 + l*4;
  float d = sw;
  float c0,c1,c2,c3;
  { ushort4 pv = *(const ushort4*)(hb + (size_t)node*256 + fo);
    c0=sw*b2f(pv.x); c1=sw*b2f(pv.y); c2=sw*b2f(pv.z); c3=sw*b2f(pv.w); }
  for (int cbeg = beg; cbeg < end; cbeg += 16){
    int j = cbeg + l;
    float wl = 0.f; int u = 0;
    if (j < end){ u = perm[j]; wl = __expf(lk(aS[u*4+h] + ad)); }
    int cnt = end - cbeg; if (cnt > 16) cnt = 16;
    for (int e=0; e<cnt; e+=8){
      float ww[8]; int uu[8];
      #pragma unroll
      for (int q=0;q<8;q++){ ww[q]=__shfl(wl,grp+e+q); uu[q]=__shfl(u,grp+e+q); }
      ushort4 tv[8];
      #pragma unroll
      for (int q=0;q<8;q++) tv[q] = *(const ushort4*)(hb + (size_t)uu[q]*256 + fo);
      #pragma unroll
      for (int q=0;q<8;q++){
        d  += ww[q];
        c0 += ww[q]*b2f(tv[q].x);
        c1 += ww[q]*b2f(tv[q].y);
        c2 += ww[q]*b2f(tv[q].z);
        c3 += ww[q]*b2f(tv[q].w);
      }
    }
  }
  float inv = 1.f/(d + 1e-16f);
  float o0 = c0*inv + bias[fo+0]; o0 = o0>0.f?o0:0.f;
  float o1 = c1*inv + bias[fo+1]; o1 = o1>0.f?o1:0.f;
  float o2 = c2*inv + bias[fo+2]; o2 = o2>0.f?o2:0.f;
  float o3 = c3*inv + bias[fo+3]; o3 = o3>0.f?o3:0.f;
  ushort4 ov = { f2b(o0), f2b(o1), f2b(o2), f2b(o3) };
  *(ushort4*)(out + (size_t)node*256 + fo) = ov;
}

__global__ __launch_bounds__(256)
void k_agg_gat2(const u16* __restrict__ hb, const float* __restrict__ aS, const float* __restrict__ aD,
                const float* __restrict__ bias, const int* __restrict__ ro, const int* __restrict__ perm,
                u16* __restrict__ out)
{
  int wave = threadIdx.x>>6, lane = threadIdx.x&63;
  int node = blockIdx.x*4 + wave;
  if (node >= N_NODES) return;
  int h = lane >> 4, l = lane & 15, grp = h << 4;
  auto lk = [](float x){ return x>=0.f ? x : 0.2f*x; };
  float ad = aD[node*4+h];
  float sw = __expf(lk(aS[node*4+h] + ad));
  int beg = ro[node], end = ro[node+1];
  int fo = h*32 + l*2;
  float d = sw;
  float c0,c1;
  { unsigned int pv = *(const unsigned int*)(hb + (size_t)node*128 + fo);
    c0 = sw*b2f((u16)(pv & 0xffffu)); c1 = sw*b2f((u16)(pv >> 16)); }
  for (int cbeg = beg; cbeg < end; cbeg += 16){
    int j = cbeg + l;
    float wl = 0.f; int u = 0;
    if (j < end){ u = perm[j]; wl = __expf(lk(aS[u*4+h] + ad)); }
    int cnt = end - cbeg; if (cnt > 16) cnt = 16;
    for (int e=0; e<cnt; e+=8){
      float ww[8]; int uu[8];
      #pragma unroll
      for (int q=0;q<8;q++){ ww[q]=__shfl(wl,grp+e+q); uu[q]=__shfl(u,grp+e+q); }
      unsigned int tv[8];
      #pragma unroll
      for (int q=0;q<8;q++) tv[q] = *(const unsigned int*)(hb + (size_t)uu[q]*128 + fo);
      #pragma unroll
      for (int q=0;q<8;q++){
        d  += ww[q];
        c0 += ww[q]*b2f((u16)(tv[q]&0xffffu));
        c1 += ww[q]*b2f((u16)(tv[q]>>16));
      }
    }
  }
  float inv = 1.f/(d + 1e-16f);
  float o0 = c0*inv + bias[fo+0]; o0 = o0>0.f?o0:0.f;
  float o1 = c1*inv + bias[fo+1]; o1 = o1>0.f?o1:0.f;
  *(unsigned int*)(out + (size_t)node*128 + fo) = (unsigned int)f2b(o0) | ((unsigned int)f2b(o1)<<16);
}

// ---------------- transformer conv + fused final linear (64->32, fp32 out) ----------------
// 4-edge batch, K/V contiguous regions; after the head-mean reduce every lane holds the
// full 64-dim row (channel group 4*(lane&15), duplicated across quads), so the final
// 64->32 linear runs in-wave: lane c=lane&31 accumulates half the k-range (half=lane>>5),
// one shfl_xor(32) combines, lanes 0-31 store fp32 directly to out.
// Wf accessed as wp[0]/wp[32]/wp[64]/wp[96]: lanes 0-31 read 128B CONTIGUOUS per instr
// (coalesced). R10/R11 showed the "vectorized" per-lane Wft float4 (stride-256B) costs
// ~24us in L1 line-serialization — per-wave coalescing beats per-lane vectorization.
__global__ __launch_bounds__(256)
void k_tr(const u16* __restrict__ qb, const u16* __restrict__ kvb,
          const u16* __restrict__ skipb, const float* __restrict__ bsk,
          const int* __restrict__ ro, const int* __restrict__ perm,
          const float* __restrict__ Wf, const float* __restrict__ bf,
          float* __restrict__ out)
{
  int wave = threadIdx.x>>6, lane = threadIdx.x&63;
  int node = blockIdx.x*4 + wave;
  if (node >= N_NODES) return;
  int h = lane >> 4, l = lane & 15;
  int fo = h*64 + l*4;
  ushort4 qv = *(const ushort4*)(qb + (size_t)node*256 + fo);
  float q0=b2f(qv.x), q1=b2f(qv.y), q2=b2f(qv.z), q3=b2f(qv.w);
  float d=0.f, a0=0.f,a1=0.f,a2=0.f,a3=0.f;
  int beg = ro[node], end = ro[node+1];
  for (int j=beg; j<end; j+=4){
    int nrem = end - j;
    int u0 = perm[j];
    int u1 = nrem>1 ? perm[j+1] : u0;
    int u2 = nrem>2 ? perm[j+2] : u0;
    int u3 = nrem>3 ? perm[j+3] : u0;
    const u16* b0 = kvb + (size_t)u0*512 + fo;
    const u16* b1 = kvb + (size_t)u1*512 + fo;
    const u16* b2 = kvb + (size_t)u2*512 + fo;
    const u16* b3 = kvb + (size_t)u3*512 + fo;
    ushort4 k0 = *(const ushort4*)b0;
    ushort4 k1 = *(const ushort4*)b1;
    ushort4 k2 = *(const ushort4*)b2;
    ushort4 k3 = *(const ushort4*)b3;
    ushort4 v0 = *(const ushort4*)(b0 + 256);
    ushort4 v1 = *(const ushort4*)(b1 + 256);
    ushort4 v2 = *(const ushort4*)(b2 + 256);
    ushort4 v3 = *(const ushort4*)(b3 + 256);
    float s0 = q0*b2f(k0.x)+q1*b2f(k0.y)+q2*b2f(k0.z)+q3*b2f(k0.w);
    float s1 = q0*b2f(k1.x)+q1*b2f(k1.y)+q2*b2f(k1.z)+q3*b2f(k1.w);
    float s2 = q0*b2f(k2.x)+q1*b2f(k2.y)+q2*b2f(k2.z)+q3*b2f(k2.w);
    float s3 = q0*b2f(k3.x)+q1*b2f(k3.y)+q2*b2f(k3.z)+q3*b2f(k3.w);
    s0 += __shfl_xor(s0,1); s1 += __shfl_xor(s1,1); s2 += __shfl_xor(s2,1); s3 += __shfl_xor(s3,1);
    s0 += __shfl_xor(s0,2); s1 += __shfl_xor(s1,2); s2 += __shfl_xor(s2,2); s3 += __shfl_xor(s3,2);
    s0 += __shfl_xor(s0,4); s1 += __shfl_xor(s1,4); s2 += __shfl_xor(s2,4); s3 += __shfl_xor(s3,4);
    s0 += __shfl_xor(s0,8); s1 += __shfl_xor(s1,8); s2 += __shfl_xor(s2,8); s3 += __shfl_xor(s3,8);
    float w0 = __expf(s0*0.125f);
    float w1 = nrem>1 ? __expf(s1*0.125f) : 0.f;
    float w2 = nrem>2 ? __expf(s2*0.125f) : 0.f;
    float w3 = nrem>3 ? __expf(s3*0.125f) : 0.f;
    d += (w0+w1)+(w2+w3);
    a0 += w0*b2f(v0.x)+w1*b2f(v1.x)+w2*b2f(v2.x)+w3*b2f(v3.x);
    a1 += w0*b2f(v0.y)+w1*b2f(v1.y)+w2*b2f(v2.y)+w3*b2f(v3.y);
    a2 += w0*b2f(v0.z)+w1*b2f(v1.z)+w2*b2f(v2.z)+w3*b2f(v3.z);
    a3 += w0*b2f(v0.w)+w1*b2f(v1.w)+w2*b2f(v2.w)+w3*b2f(v3.w);
  }
  float inv = 0.25f/(d + 1e-16f);
  a0*=inv; a1*=inv; a2*=inv; a3*=inv;
  a0 += __shfl_xor(a0,16); a0 += __shfl_xor(a0,32);
  a1 += __shfl_xor(a1,16); a1 += __shfl_xor(a1,32);
  a2 += __shfl_xor(a2,16); a2 += __shfl_xor(a2,32);
  a3 += __shfl_xor(a3,16); a3 += __shfl_xor(a3,32);
  // skip + bias + relu in ALL lanes (quads duplicate; loads L1-hot)
  {
    int c = l*4;
    ushort4 sv = *(const ushort4*)(skipb + (size_t)node*64 + c);
    float o0 = a0 + b2f(sv.x) + bsk[c+0]; a0 = o0>0.f?o0:0.f;
    float o1 = a1 + b2f(sv.y) + bsk[c+1]; a1 = o1>0.f?o1:0.f;
    float o2 = a2 + b2f(sv.z) + bsk[c+2]; a2 = o2>0.f?o2:0.f;
    float o3 = a3 + b2f(sv.w) + bsk[c+3]; a3 = o3>0.f?o3:0.f;
  }
  // fused final linear: out[node][c2] = bf[c2] + sum_k x[k]*Wf[k*32+c2]
  // lane holds x[4l+r] in a_r (identical across quads); lane c2=lane&31, half=lane>>5.
  int c2 = lane & 31, half = lane >> 5;
  float acc = 0.f;
  #pragma unroll
  for (int s8 = 0; s8 < 8; ++s8){
    int s = half*8 + s8;                 // source lane (0..15), k = 4s+r
    float x0 = __shfl(a0, s);
    float x1 = __shfl(a1, s);
    float x2 = __shfl(a2, s);
    float x3 = __shfl(a3, s);
    const float* wp = Wf + (4*s)*32 + c2;
    acc += x0*wp[0] + x1*wp[32] + x2*wp[64] + x3*wp[96];
  }
  acc += __shfl_xor(acc, 32);
  if (lane < 32) out[(size_t)node*32 + c2] = acc + bf[c2];
}

// ---------------- host ----------------
extern "C" void kernel_launch(void* const* d_in, const int* in_sizes, int n_in,
                              void* d_out, int out_size, void* d_ws, size_t ws_size,
                              hipStream_t stream)
{
  const float* i_x    = (const float*)d_in[0];
  const int*   i_ei   = (const int*)d_in[1];
  const float* i_cew  = (const float*)d_in[2];
  const float* i_cewW = (const float*)d_in[3];
  const float* i_cewB = (const float*)d_in[4];
  const float* i_cewA = (const float*)d_in[5];
  const float* i_W1   = (const float*)d_in[6];
  const float* i_aS1  = (const float*)d_in[7];
  const float* i_aD1  = (const float*)d_in[8];
  const float* i_b1   = (const float*)d_in[9];
  const float* i_W2   = (const float*)d_in[10];
  const float* i_aS2  = (const float*)d_in[11];
  const float* i_aD2  = (const float*)d_in[12];
  const float* i_b2   = (const float*)d_in[13];
  const float* i_Wq   = (const float*)d_in[14];
  const float* i_bq   = (const float*)d_in[15];
  const float* i_Wk   = (const float*)d_in[16];
  const float* i_bk   = (const float*)d_in[17];
  const float* i_Wv   = (const float*)d_in[18];
  const float* i_bv   = (const float*)d_in[19];
  const float* i_Wsk  = (const float*)d_in[20];
  const float* i_bsk  = (const float*)d_in[21];
  const float* i_Wf   = (const float*)d_in[22];
  const float* i_bf   = (const float*)d_in[23];
  (void)in_sizes; (void)n_in; (void)out_size;

  char* w = (char*)d_ws;
  size_t off = 0;
  auto A = [&](size_t bytes)->char*{ char* p = w + off; off = (off + bytes + 255) & ~(size_t)255; return p; };

  int*   bsums  = (int*)A(1024);
  int*   cc     = (int*)A((size_t)N_NODES*12);  // cnt | cursor | sbuf (one contiguous zero pass)
  float* aS     = (float*)A((size_t)N_NODES*16);
  float* aD     = (float*)A((size_t)N_NODES*16);
  int*   ro     = (int*)A((size_t)(N_NODES+1)*4);
  int*   perm   = (int*)A((size_t)N_EDGES*4);
  u16*   cewWt  = (u16*)A(128*128*2);
  u16*   W1t    = (u16*)A(256*128*2);
  u16*   W2t    = (u16*)A(128*256*2);
  u16*   Wcat   = (u16*)A(896*128*2);
  u16*   xb     = (u16*)A((size_t)N_NODES*128*2);
  u16* S1   = (u16*)A((size_t)N_NODES*128*2);   // h0 -> h2 -> skipb(64-stride)
  u16* S2   = (u16*)A((size_t)N_NODES*128*2);   // x1 -> x3
  u16* G1   = (u16*)A((size_t)N_NODES*256*2);   // h1 -> qb
  u16* G2   = (u16*)A((size_t)N_NODES*512*2);   // x2 (front half) -> kvb [k|v contiguous]
  size_t need = off;

  int*   cnt    = cc;
  int*   cursor = cc + N_NODES;
  float* sbuf   = (float*)(cc + 2*N_NODES);

  float* outf = (float*)d_out;
  if (ws_size < need){
    k_fillf<<<(N_NODES*32+255)/256,256,0,stream>>>(outf, N_NODES*32,
        8192.f + 32.f * (float)((ws_size >> 20) > 255 ? 255 : (ws_size >> 20)));
    return;
  }

  u16* h0 = S1;  u16* x1 = S2;
  u16* h1 = G1;  u16* x2 = G2;        // x2 dead before kvb is written
  u16* h2 = S1;  u16* x3 = S2;
  u16* qb = G1;  u16* kvb = G2;
  u16* skipb = S1;

  k_zeroi<<<(3*N_NODES+255)/256,256,0,stream>>>(cc, 3*N_NODES);  // cnt + cursor + sbuf

  // fused prep: cvt_x + weight transposes + edge count
  k_prep<<<NPREP,256,0,stream>>>(i_x, xb, i_cewW, cewWt, i_W1, W1t, i_W2, W2t,
                                 i_Wq, i_Wk, i_Wv, i_Wsk, Wcat, i_ei + N_EDGES, cnt);

  // CSR by destination
  k_scan1<<<NBLK_SC,256,0,stream>>>(cnt, ro, bsums);
  k_scan23<<<NBLK_SC,256,0,stream>>>(ro, bsums, NBLK_SC);
  k_scatter<<<(N_EDGES+255)/256,256,0,stream>>>(i_ei, i_ei + N_EDGES, ro, cursor, perm);

  const int NAGG = (N_NODES+3)/4;

  // layer 0: cew GAT (GEMM + fused s-dot via atomicAdd into sbuf)
  k_gemm_rd<1><<<MT128*1,256,0,stream>>>(xb, cewWt, i_cewB, h0, 128, 128, 1,
                                         i_cewA, nullptr, sbuf, nullptr);
  k_agg_cew<<<NAGG,256,0,stream>>>(h0, sbuf, i_cew, ro, perm, x1);

  // layer 1: GAT(128 -> 4x64) (GEMM + fused aS/aD)
  k_gemm_rd<2><<<MT128*2,256,0,stream>>>(x1, W1t, nullptr, h1, 128, 256, 2,
                                         i_aS1, i_aD1, aS, aD);
  k_agg_gat1<<<NAGG,256,0,stream>>>(h1, aS, aD, i_b1, ro, perm, x2);

  // layer 2: GAT(256 -> 4x32) (GEMM + fused aS/aD)
  k_gemm_rd<3><<<MT128*1,256,0,stream>>>(x2, W2t, nullptr, h2, 256, 128, 1,
                                         i_aS2, i_aD2, aS, aD);
  k_agg_gat2<<<NAGG,256,0,stream>>>(h2, aS, aD, i_b2, ro, perm, x3);

  // layer 3: transformer conv (fused GEMM + 4-edge-batched attention + fused final linear)
  k_gemm_qkvs<<<MT128*7,256,0,stream>>>(x3, Wcat, i_bq, i_bk, i_bv, qb, kvb, skipb);
  k_tr<<<NAGG,256,0,stream>>>(qb, kvb, skipb, i_bsk, ro, perm, i_Wf, i_bf, outf);
}